// Round 13
// baseline (305.898 us; speedup 1.0000x reference)
//
#include <hip/hip_runtime.h>

typedef unsigned short us16;
typedef __bf16 bf16x8 __attribute__((ext_vector_type(8)));
typedef float f32x2 __attribute__((ext_vector_type(2)));
typedef float f32x4 __attribute__((ext_vector_type(4)));
typedef float f32x16 __attribute__((ext_vector_type(16)));
typedef unsigned u32x4 __attribute__((ext_vector_type(4)));

#define DEV __device__ __forceinline__

DEV us16 f2bf(float x) {
  union { float f; unsigned u; } un; un.f = x;
  unsigned r = un.u + 0x7fffu + ((un.u >> 16) & 1u);
  return (us16)(r >> 16);
}
DEV float bf2f(us16 u) {
  union { unsigned u; float f; } x; x.u = ((unsigned)u) << 16; return x.f;
}
DEV float gelu_f(float x) {
  float u = 0.7978845608028654f * (x + 0.044715f * x * x * x);
  float e = __expf(2.0f * u);
  return x * (1.0f - 1.0f / (e + 1.0f));
}

DEV f32x16 mfma32(bf16x8 a, bf16x8 b, f32x16 c) {
  return __builtin_amdgcn_mfma_f32_32x32x16_bf16(a, b, c, 0, 0, 0);
}

DEV unsigned cvtpk_bf16(float lo, float hi) {
  unsigned r;
  asm("v_cvt_pk_bf16_f32 %0, %1, %2" : "=v"(r) : "v"(lo), "v"(hi));
  return r;
}
DEV void plswap(unsigned& x, unsigned& y) {
  asm("v_permlane32_swap_b32 %0, %1" : "+v"(x), "+v"(y));
}

// global -> LDS direct load, 16B per lane. LDS dest is wave-uniform base + lane*16.
DEV void gll16(const void* gp, void* lp) {
  __builtin_amdgcn_global_load_lds(
      (__attribute__((address_space(1))) unsigned int*)(unsigned long long)(gp),
      (__attribute__((address_space(3))) unsigned int*)(unsigned int)(unsigned long long)(lp),
      16, 0, 0);
}

// ---------------- prep: tp = gelu(time_emb) @ Wt + bt  -> tp[2][2048] ----------------
__global__ __launch_bounds__(256) void prep_tp(const float* __restrict__ te,
                                               const float* __restrict__ Wt,
                                               const float* __restrict__ bt,
                                               float* __restrict__ tp) {
  __shared__ float ge[1024];
  __shared__ float red[256];
  const int b = blockIdx.y, jt = blockIdx.x, t = threadIdx.x;
  for (int i = t; i < 1024; i += 256) ge[i] = gelu_f(te[b * 1024 + i]);
  __syncthreads();
  const int j = jt * 64 + (t & 63);
  const int dg = t >> 6;
  float acc = 0.f;
  for (int i = 0; i < 256; ++i) {
    int d = dg * 256 + i;
    acc += ge[d] * Wt[(size_t)d * 2048 + j];
  }
  red[t] = acc;
  __syncthreads();
  if (t < 64) tp[b * 2048 + jt * 64 + t] =
      red[t] + red[64 + t] + red[128 + t] + red[192 + t] + bt[jt * 64 + t];
}

// ---------------- weight cast+transpose: W[K][N] f32 -> Wt[N][K] bf16 ----------------
__global__ __launch_bounds__(256) void transpose_cast(const float* __restrict__ W,
                                                      us16* __restrict__ Wo,
                                                      int K, int N) {
  __shared__ float t[32][33];
  const int bn = blockIdx.x * 32, bk = blockIdx.y * 32;
  const int tx = threadIdx.x & 31, ty = threadIdx.x >> 5;
#pragma unroll
  for (int j = 0; j < 32; j += 8) t[ty + j][tx] = W[(size_t)(bk + ty + j) * N + bn + tx];
  __syncthreads();
#pragma unroll
  for (int j = 0; j < 32; j += 8) Wo[(size_t)(bn + ty + j) * K + bk + tx] = f2bf(t[tx][ty + j]);
}

// ---------------- LayerNorm (+ optional AdaLN modulation), f32 in -> bf16 out --------
template <int MOD>
__global__ __launch_bounds__(256) void ln_kernel(const float* __restrict__ x,
                                                 const float* __restrict__ gw,
                                                 const float* __restrict__ bw,
                                                 const float* __restrict__ tp,
                                                 us16* __restrict__ out) {
  const int row = blockIdx.x, b = row >> 11, t = threadIdx.x;
  const int lane = t & 63, wid = t >> 6;
  float4 xv = ((const float4*)(x + (size_t)row * 1024))[t];
  float s = xv.x + xv.y + xv.z + xv.w;
  float s2 = xv.x * xv.x + xv.y * xv.y + xv.z * xv.z + xv.w * xv.w;
#pragma unroll
  for (int o = 32; o; o >>= 1) { s += __shfl_xor(s, o); s2 += __shfl_xor(s2, o); }
  __shared__ float rs_[4], rq_[4];
  if (lane == 0) { rs_[wid] = s; rq_[wid] = s2; }
  __syncthreads();
  s = rs_[0] + rs_[1] + rs_[2] + rs_[3];
  s2 = rq_[0] + rq_[1] + rq_[2] + rq_[3];
  const float mu = s * 0.0009765625f;
  const float var = s2 * 0.0009765625f - mu * mu;
  const float rsig = rsqrtf(var + 1e-5f);
  float4 gv = ((const float4*)gw)[t], bv = ((const float4*)bw)[t];
  float y[4] = {(xv.x - mu) * rsig * gv.x + bv.x, (xv.y - mu) * rsig * gv.y + bv.y,
                (xv.z - mu) * rsig * gv.z + bv.z, (xv.w - mu) * rsig * gv.w + bv.w};
  if (MOD) {
    float4 sc = ((const float4*)(tp + b * 2048))[t];
    float4 sh = ((const float4*)(tp + b * 2048 + 1024))[t];
    y[0] = y[0] * (1.f + sc.x) + sh.x;
    y[1] = y[1] * (1.f + sc.y) + sh.y;
    y[2] = y[2] * (1.f + sc.z) + sh.z;
    y[3] = y[3] * (1.f + sc.w) + sh.w;
  }
  ushort4 o = {f2bf(y[0]), f2bf(y[1]), f2bf(y[2]), f2bf(y[3])};
  ((ushort4*)(out + (size_t)row * 1024))[t] = o;
}

// ---------------- dist permute: f32 [2048][2048] -> dp bf16 per-lane layout ----------
// dp[Q][t][ks][l][e] = dist[Q*32 + (l&31)][t*64 + ks*8 + (l>>5)*4 + e]
__global__ __launch_bounds__(256) void permute_dist(const float* __restrict__ dist,
                                                    us16* __restrict__ dp) {
  const int Q = blockIdx.x >> 3, part = blockIdx.x & 7;
  for (int j = threadIdx.x; j < 2048; j += 256) {
    int i = part * 2048 + j;
    int l = i & 63, ks = (i >> 6) & 7, t = i >> 9;
    int row = Q * 32 + (l & 31);
    int col = t * 64 + ks * 8 + (l >> 5) * 4;
    float4 v = *(const float4*)(dist + (size_t)row * 2048 + col);
    ushort4 o = {f2bf(v.x), f2bf(v.y), f2bf(v.z), f2bf(v.w)};
    *(ushort4*)(dp + ((size_t)Q * 16384 + i) * 4) = o;
  }
}

// ---------------- V transpose: v[bh][2048][64] -> vt[bh][64][2048] ----------------
__global__ __launch_bounds__(256) void transpose_v(const us16* __restrict__ v,
                                                   us16* __restrict__ vt) {
  __shared__ us16 t[64][72];
  const int bh = blockIdx.y, kv0 = blockIdx.x * 64;
  const int tid = threadIdx.x;
  const int r = tid >> 2, c0 = (tid & 3) * 16;
  const us16* src = v + ((size_t)bh * 2048 + kv0 + r) * 64 + c0;
  *(uint4*)&t[r][c0] = *(const uint4*)src;
  *(uint4*)&t[r][c0 + 8] = *(const uint4*)(src + 8);
  __syncthreads();
  const int d = tid >> 2, kvl = (tid & 3) * 16;
  us16 buf[16];
#pragma unroll
  for (int i = 0; i < 16; ++i) buf[i] = t[kvl + i][d];
  us16* dst = vt + ((size_t)bh * 64 + d) * 2048 + kv0 + kvl;
  *(uint4*)dst = *(uint4*)buf;
  *(uint4*)(dst + 8) = *(uint4*)(buf + 8);
}

// ---------------- GEMM: C[M][N] = A[M][K] @ Bt[N][K]^T, bf16 in, f32 acc -------------
// 32x32x16 MFMA. EPI 4 = split-K bf16 partials: z-slice g covers K/2, writes p_g.
template <int EPI>
__global__ __launch_bounds__(256) void gemm_bt(const us16* __restrict__ A,
                                               const us16* __restrict__ Bt,
                                               int M, int N, int K,
                                               const float* __restrict__ addf,
                                               const float* __restrict__ bias,
                                               float* __restrict__ outf,
                                               us16* __restrict__ outh,
                                               us16* __restrict__ qb,
                                               us16* __restrict__ kb,
                                               us16* __restrict__ vb) {
  __shared__ us16 Al[128 * 64];
  __shared__ us16 Bl[128 * 64];
  const int tid = threadIdx.x, lane = tid & 63, wid = tid >> 6;
  const int wm = wid >> 1, wn = wid & 1;
  const int nbx = gridDim.x, nwg = nbx * gridDim.y;
  const int idlin = blockIdx.y * nbx + blockIdx.x;
  const int wg = (idlin & 7) * (nwg >> 3) + (idlin >> 3);
  const int bm = wg / nbx, bn = wg % nbx;
  const int q31 = lane & 31, hi = lane >> 5;
  const int srow = lane >> 3;
  const int scol = ((lane & 7) ^ srow) << 3;

  f32x16 acc[2][2] = {};
  const size_t arow0 = (size_t)bm * 128 + wid * 32 + srow;
  const size_t brow0 = (size_t)bn * 128 + wid * 32 + srow;

  int kbeg = 0, kend = K;
  if (EPI == 4) { kbeg = blockIdx.z * (K >> 1); kend = kbeg + (K >> 1); }

  for (int k0 = kbeg; k0 < kend; k0 += 64) {
#pragma unroll
    for (int j = 0; j < 4; ++j) {
      gll16(A + (arow0 + j * 8) * K + k0 + scol, (char*)Al + (wid * 32 + j * 8) * 128);
      gll16(Bt + (brow0 + j * 8) * K + k0 + scol, (char*)Bl + (wid * 32 + j * 8) * 128);
    }
    __syncthreads();
#pragma unroll
    for (int ks = 0; ks < 4; ++ks) {
      const int cb = ks * 32 + hi * 16;
      bf16x8 af[2], bfr[2];
#pragma unroll
      for (int i = 0; i < 2; ++i) {
        int ra = wm * 64 + i * 32 + q31;
        af[i] = *(const bf16x8*)((const char*)Al + ra * 128 + (cb ^ ((ra & 7) << 4)));
        int rb = wn * 64 + i * 32 + q31;
        bfr[i] = *(const bf16x8*)((const char*)Bl + rb * 128 + (cb ^ ((rb & 7) << 4)));
      }
#pragma unroll
      for (int mi = 0; mi < 2; ++mi)
#pragma unroll
        for (int ni = 0; ni < 2; ++ni)
          acc[mi][ni] = mfma32(af[mi], bfr[ni], acc[mi][ni]);
    }
    __syncthreads();
  }

  us16* pd = nullptr;
  if (EPI == 4) pd = blockIdx.z == 0 ? outh : qb;

#pragma unroll
  for (int mi = 0; mi < 2; ++mi)
#pragma unroll
    for (int ni = 0; ni < 2; ++ni)
#pragma unroll
      for (int r = 0; r < 16; ++r) {
        int grow = bm * 128 + wm * 64 + mi * 32 + (r & 3) + 8 * (r >> 2) + 4 * hi;
        int gcol = bn * 128 + wn * 64 + ni * 32 + q31;
        float v = acc[mi][ni][r];
        if (EPI == 0) {
          int b = grow >> 11, lseq = grow & 2047;
          int which = gcol >> 10, hc = gcol & 1023;
          int hh = hc >> 6, d = hc & 63;
          size_t o = ((size_t)(b * 16 + hh) * 2048 + lseq) * 64 + d;
          if (which == 0) qb[o] = f2bf(v * 0.1803368801f);  // 0.125 * log2(e)
          else if (which == 1) kb[o] = f2bf(v);
          else vb[o] = f2bf(v);
        } else if (EPI == 1) {
          outh[(size_t)grow * N + gcol] = f2bf(gelu_f(v + bias[gcol]));
        } else if (EPI == 2) {
          size_t o = (size_t)grow * N + gcol;
          outf[o] = addf[o] + v;
        } else if (EPI == 4) {
          pd[(size_t)grow * N + gcol] = f2bf(v);
        } else {
          size_t o = (size_t)grow * N + gcol;
          outf[o] = addf[o] + bias[gcol] + v;
        }
      }
}

// ---------------- MLP2 combine: out = x1 + b2 + p0 + p1 ----------------
__global__ __launch_bounds__(256) void combine_mlp2(const float* __restrict__ x1,
                                                    const float* __restrict__ b2,
                                                    const us16* __restrict__ p0,
                                                    const us16* __restrict__ p1,
                                                    float* __restrict__ out) {
  const int row = blockIdx.x, t = threadIdx.x;
  const size_t base = (size_t)row * 1024 + t * 4;
  float4 xv = *(const float4*)(x1 + base);
  float4 bv = *(const float4*)(b2 + t * 4);
  ushort4 a = *(const ushort4*)(p0 + base);
  ushort4 b = *(const ushort4*)(p1 + base);
  float4 o;
  o.x = xv.x + bv.x + bf2f(a.x) + bf2f(b.x);
  o.y = xv.y + bv.y + bf2f(a.y) + bf2f(b.y);
  o.z = xv.z + bv.z + bf2f(a.z) + bf2f(b.z);
  o.w = xv.w + bv.w + bf2f(a.w) + bf2f(b.w);
  *(float4*)(out + base) = o;
}

// ---------------- flash attention: swapped-QK^T 32x32, exp2, pk-f32 ------------------
// grid (qt=16, bh=32), qt fastest, no swizzle. 4 waves x 32 q-rows; 32 kv tiles.
// COUNTED-VMCNT PIPELINE: 3 K/V LDS buffers; per tile: s_waitcnt vmcnt(12) (keeps the
// latest batch of 12 VMEM ops [4 gll16 + 8 dist reg-loads] in flight) + raw s_barrier,
// THEN issue the next batch, then compute. Loads get a full tile of compute to land;
// no vmcnt(0) drain per tile (the __syncthreads stall this replaces).
typedef union { f32x16 v; f32x2 p[8]; float f[16]; } F16U;

__global__ __launch_bounds__(256) void attn_kernel(const us16* __restrict__ q,
                                                   const us16* __restrict__ k,
                                                   const us16* __restrict__ vt,
                                                   const us16* __restrict__ dp,
                                                   const float* __restrict__ tscale,
                                                   us16* __restrict__ ctx) {
  __shared__ __align__(16) us16 Kl[3][64 * 64];
  __shared__ __align__(16) us16 Vl[3][64 * 64];
  __shared__ float als[128];
  const int tid = threadIdx.x, l = tid & 63, w4 = tid >> 6;
  const int q31 = l & 31, hi = l >> 5;
  const int qt = blockIdx.x, bh = blockIdx.y;
  const int b = bh >> 4, hh = bh & 15;
  const float scaleL = tscale[hh] * 1.44269504f;  // exp2 domain
  const int srow = l >> 3;
  const int scol = ((l & 7) ^ srow) << 3;
  const int q0blk = qt * 128;

  const us16* qg = q + ((size_t)bh * 2048 + q0blk + w4 * 32 + q31) * 64;
  bf16x8 qf[4];
#pragma unroll
  for (int kd = 0; kd < 4; ++kd) qf[kd] = *(const bf16x8*)(qg + kd * 16 + hi * 8);

  const us16* kpb = k + (size_t)bh * 2048 * 64;
  const us16* vpb = vt + (size_t)bh * 64 * 2048;
  const us16* dpw = dp + ((size_t)(qt * 4 + w4) * 16384 + l) * 4;

  f32x16 Oa = {}, Ob = {};
  float m = -1e30f, lsum = 0.f;
  ushort4 dA[8], dB[8];

  auto stage = [&](int kvn, int bufsel) {
#pragma unroll
    for (int j = 0; j < 2; ++j) {
      int row = w4 * 16 + j * 8 + srow;
      gll16(kpb + (size_t)(kvn + row) * 64 + scol, (char*)&Kl[bufsel][0] + (w4 * 16 + j * 8) * 128);
      gll16(vpb + (size_t)row * 2048 + kvn + scol, (char*)&Vl[bufsel][0] + (w4 * 16 + j * 8) * 128);
    }
  };
  auto load_d = [&](ushort4* dst, int tabs) {
#pragma unroll
    for (int ks = 0; ks < 8; ++ks) dst[ks] = *(const ushort4*)(dpw + (tabs * 8 + ks) * 256);
  };

  auto tile = [&](const us16* Kb, const us16* Vb, const ushort4* dc) {
    f32x16 SAv = {}, SBv = {};
#pragma unroll
    for (int kd = 0; kd < 4; ++kd) {
      const int cb = kd * 32 + hi * 16;
      const int r0 = q31, r1 = 32 + q31;
      bf16x8 ka = *(const bf16x8*)((const char*)Kb + r0 * 128 + (cb ^ ((r0 & 7) << 4)));
      bf16x8 kb2 = *(const bf16x8*)((const char*)Kb + r1 * 128 + (cb ^ ((r1 & 7) << 4)));
      SAv = mfma32(ka, qf[kd], SAv);
      SBv = mfma32(kb2, qf[kd], SBv);
    }
    F16U A, B2;
    A.v = SAv;
    B2.v = SBv;

    f32x2 t0 = __builtin_elementwise_max(__builtin_elementwise_max(A.p[0], A.p[1]),
                                         __builtin_elementwise_max(A.p[2], A.p[3]));
    f32x2 t1 = __builtin_elementwise_max(__builtin_elementwise_max(A.p[4], A.p[5]),
                                         __builtin_elementwise_max(A.p[6], A.p[7]));
    f32x2 t2 = __builtin_elementwise_max(__builtin_elementwise_max(B2.p[0], B2.p[1]),
                                         __builtin_elementwise_max(B2.p[2], B2.p[3]));
    f32x2 t3 = __builtin_elementwise_max(__builtin_elementwise_max(B2.p[4], B2.p[5]),
                                         __builtin_elementwise_max(B2.p[6], B2.p[7]));
    f32x2 tt = __builtin_elementwise_max(__builtin_elementwise_max(t0, t1),
                                         __builtin_elementwise_max(t2, t3));
    float pm = fmaxf(tt[0], tt[1]);
    pm = fmaxf(pm, __shfl_xor(pm, 32));

    if (__any(pm > m + 11.53f)) {  // 8 * log2(e)
      float mn = fmaxf(m, pm);
      float al = __builtin_exp2f(m - mn);
      m = mn;
      lsum *= al;
      if (!hi) als[w4 * 32 + q31] = al;
      f32x4 av[4];
#pragma unroll
      for (int g2 = 0; g2 < 4; ++g2) av[g2] = *(const f32x4*)&als[w4 * 32 + g2 * 8 + hi * 4];
#pragma unroll
      for (int g2 = 0; g2 < 4; ++g2)
#pragma unroll
        for (int e = 0; e < 4; ++e) {
          Oa[g2 * 4 + e] *= av[g2][e];
          Ob[g2 * 4 + e] *= av[g2][e];
        }
    }

    f32x2 nm = {-m, -m};
    f32x2 ns = {-scaleL, -scaleL};
#pragma unroll
    for (int ks = 0; ks < 4; ++ks) {
      ushort4 dlo = dc[ks], dhi = dc[ks + 4];
      f32x2 l0 = {bf2f(dlo.x), bf2f(dlo.y)};
      f32x2 l1 = {bf2f(dlo.z), bf2f(dlo.w)};
      f32x2 h0 = {bf2f(dhi.x), bf2f(dhi.y)};
      f32x2 h1 = {bf2f(dhi.z), bf2f(dhi.w)};
      A.p[ks * 2] = __builtin_elementwise_fma(ns, l0, A.p[ks * 2] + nm);
      A.p[ks * 2 + 1] = __builtin_elementwise_fma(ns, l1, A.p[ks * 2 + 1] + nm);
      B2.p[ks * 2] = __builtin_elementwise_fma(ns, h0, B2.p[ks * 2] + nm);
      B2.p[ks * 2 + 1] = __builtin_elementwise_fma(ns, h1, B2.p[ks * 2 + 1] + nm);
    }
#pragma unroll
    for (int i = 0; i < 16; ++i) {
      A.f[i] = __builtin_exp2f(A.f[i]);
      B2.f[i] = __builtin_exp2f(B2.f[i]);
    }

    f32x2 s = ((A.p[0] + A.p[1]) + (A.p[2] + A.p[3])) + ((A.p[4] + A.p[5]) + (A.p[6] + A.p[7]));
    s = s + (((B2.p[0] + B2.p[1]) + (B2.p[2] + B2.p[3])) +
             ((B2.p[4] + B2.p[5]) + (B2.p[6] + B2.p[7])));
    float rs = s[0] + s[1];
    rs += __shfl_xor(rs, 32);
    lsum += rs;

#pragma unroll
    for (int ks = 0; ks < 4; ++ks) {
      float p0, p1, p2, p3, p4, p5, p6, p7;
      if (ks == 0) { p0=A.f[0];p1=A.f[1];p2=A.f[2];p3=A.f[3];p4=A.f[4];p5=A.f[5];p6=A.f[6];p7=A.f[7]; }
      else if (ks == 1) { p0=A.f[8];p1=A.f[9];p2=A.f[10];p3=A.f[11];p4=A.f[12];p5=A.f[13];p6=A.f[14];p7=A.f[15]; }
      else if (ks == 2) { p0=B2.f[0];p1=B2.f[1];p2=B2.f[2];p3=B2.f[3];p4=B2.f[4];p5=B2.f[5];p6=B2.f[6];p7=B2.f[7]; }
      else { p0=B2.f[8];p1=B2.f[9];p2=B2.f[10];p3=B2.f[11];p4=B2.f[12];p5=B2.f[13];p6=B2.f[14];p7=B2.f[15]; }
      unsigned a = cvtpk_bf16(p0, p1), c = cvtpk_bf16(p2, p3);
      unsigned bb = cvtpk_bf16(p4, p5), dd = cvtpk_bf16(p6, p7);
      plswap(a, bb);
      plswap(c, dd);
      u32x4 fw;
      fw[0] = a; fw[1] = c; fw[2] = bb; fw[3] = dd;
      bf16x8 pf = __builtin_bit_cast(bf16x8, fw);
      const int cb = ks * 32 + hi * 16;
      const int rv0 = q31, rv1 = 32 + q31;
      bf16x8 v0 = *(const bf16x8*)((const char*)Vb + rv0 * 128 + (cb ^ ((rv0 & 7) << 4)));
      Oa = mfma32(pf, v0, Oa);
      bf16x8 v1 = *(const bf16x8*)((const char*)Vb + rv1 * 128 + (cb ^ ((rv1 & 7) << 4)));
      Ob = mfma32(pf, v1, Ob);
    }
  };

  // prologue: issue tiles 0 and 1 (batches of 12 VMEM each: 4 gll16 + 8 dist loads)
  stage(0, 0);
  load_d(dA, 0);
  stage(64, 1);
  load_d(dB, 1);

  for (int t = 0; t < 32; t += 2) {
    // even tile t: need stage(t) complete; outstanding allowed = latest batch (12)
    asm volatile("s_waitcnt vmcnt(12)" ::: "memory");
    __builtin_amdgcn_s_barrier();
    if (t + 2 < 32) {
      stage((t + 2) * 64, (t + 2) % 3);
      load_d(dA, t + 2);  // dA free: consumed by this tile() via copy below? no — dA is cur!
    }
    tile(&Kl[t % 3][0], &Vl[t % 3][0], dA);
    // odd tile t+1
    if (t + 1 == 31) {
      asm volatile("s_waitcnt vmcnt(0)" ::: "memory");
    } else {
      asm volatile("s_waitcnt vmcnt(12)" ::: "memory");
    }
    __builtin_amdgcn_s_barrier();
    if (t + 3 < 32) {
      stage((t + 3) * 64, (t + 3) % 3);
      load_d(dB, t + 3);
    }
    tile(&Kl[(t + 1) % 3][0], &Vl[(t + 1) % 3][0], dB);
  }

  // normalize + store
  float rl = 1.f / lsum;
  if (!hi) als[w4 * 32 + q31] = rl;
  f32x4 rv[4];
#pragma unroll
  for (int g2 = 0; g2 < 4; ++g2) rv[g2] = *(const f32x4*)&als[w4 * 32 + g2 * 8 + hi * 4];
  us16* cb_ = ctx + ((size_t)b * 2048 + q0blk + w4 * 32) * 1024 + hh * 64;
#pragma unroll
  for (int g2 = 0; g2 < 4; ++g2)
#pragma unroll
    for (int e = 0; e < 4; ++e) {
      int r = g2 * 4 + e;
      int qrow = g2 * 8 + hi * 4 + e;
      cb_[(size_t)qrow * 1024 + q31] = f2bf(Oa[r] * rv[g2][e]);
      cb_[(size_t)qrow * 1024 + 32 + q31] = f2bf(Ob[r] * rv[g2][e]);
    }
}

extern "C" void kernel_launch(void* const* d_in, const int* in_sizes, int n_in,
                              void* d_out, int out_size, void* d_ws, size_t ws_size,
                              hipStream_t stream) {
  const float* x    = (const float*)d_in[0];
  const float* dist = (const float*)d_in[1];
  const float* te   = (const float*)d_in[2];
  const float* ln1g = (const float*)d_in[4];
  const float* ln1b = (const float*)d_in[5];
  const float* Wqkv = (const float*)d_in[6];
  const float* Wout = (const float*)d_in[7];
  const float* tsc  = (const float*)d_in[8];
  const float* ln2g = (const float*)d_in[9];
  const float* ln2b = (const float*)d_in[10];
  const float* W1   = (const float*)d_in[11];
  const float* b1   = (const float*)d_in[12];
  const float* W2   = (const float*)d_in[13];
  const float* b2   = (const float*)d_in[14];
  const float* Wtm  = (const float*)d_in[15];
  const float* btm  = (const float*)d_in[16];
  float* out = (float*)d_out;
  (void)in_sizes; (void)n_in; (void)out_size; (void)ws_size;

  char* w = (char*)d_ws;
  size_t off = 0;
  auto alloc = [&](size_t bytes) { size_t o = off; off += (bytes + 255) & ~(size_t)255; return o; };
  float* tp  = (float*)(w + alloc((size_t)2 * 2048 * 4));
  us16* h    = (us16*)(w + alloc((size_t)4096 * 1024 * 2));
  us16* wqkvT= (us16*)(w + alloc((size_t)3072 * 1024 * 2));
  us16* woutT= (us16*)(w + alloc((size_t)1024 * 1024 * 2));
  us16* w1T  = (us16*)(w + alloc((size_t)4096 * 1024 * 2));
  us16* w2T  = (us16*)(w + alloc((size_t)1024 * 4096 * 2));
  us16* qb   = (us16*)(w + alloc((size_t)4 * 4096 * 1024 * 2));
  us16* kb   = qb + (size_t)4096 * 1024;
  us16* vb   = kb + (size_t)4096 * 1024;
  us16* vtb  = vb + (size_t)4096 * 1024;
  us16* gbuf = qb;  // reused after attention for MLP hidden [4096][4096]
  us16* dp   = (us16*)(w + alloc((size_t)2048 * 2048 * 2));
  us16* ctx  = (us16*)(w + alloc((size_t)4096 * 1024 * 2));
  float* x1  = (float*)(w + alloc((size_t)4096 * 1024 * 4));
  us16* h2   = (us16*)(w + alloc((size_t)4096 * 1024 * 2));
  us16* mp0  = dp;   // MLP2 split-K partials (dp free after attn)
  us16* mp1  = ctx;  // (ctx free after Wout gemm)

  prep_tp<<<dim3(32, 2), 256, 0, stream>>>(te, Wtm, btm, tp);
  transpose_cast<<<dim3(96, 32), 256, 0, stream>>>(Wqkv, wqkvT, 1024, 3072);
  transpose_cast<<<dim3(32, 32), 256, 0, stream>>>(Wout, woutT, 1024, 1024);
  transpose_cast<<<dim3(128, 32), 256, 0, stream>>>(W1, w1T, 1024, 4096);
  transpose_cast<<<dim3(32, 128), 256, 0, stream>>>(W2, w2T, 4096, 1024);
  ln_kernel<1><<<4096, 256, 0, stream>>>(x, ln1g, ln1b, tp, h);
  permute_dist<<<512, 256, 0, stream>>>(dist, dp);
  gemm_bt<0><<<dim3(24, 32), 256, 0, stream>>>(h, wqkvT, 4096, 3072, 1024,
                                               nullptr, nullptr, nullptr, nullptr, qb, kb, vb);
  transpose_v<<<dim3(32, 32), 256, 0, stream>>>(vb, vtb);
  attn_kernel<<<dim3(16, 32), 256, 0, stream>>>(qb, kb, vtb, dp, tsc, ctx);
  gemm_bt<2><<<dim3(8, 32), 256, 0, stream>>>(ctx, woutT, 4096, 1024, 1024,
                                              x, nullptr, x1, nullptr, nullptr, nullptr, nullptr);
  ln_kernel<0><<<4096, 256, 0, stream>>>(x1, ln2g, ln2b, nullptr, h2);
  gemm_bt<1><<<dim3(32, 32), 256, 0, stream>>>(h2, w1T, 4096, 4096, 1024,
                                               nullptr, b1, nullptr, gbuf, nullptr, nullptr, nullptr);
  gemm_bt<4><<<dim3(8, 32, 2), 256, 0, stream>>>(gbuf, w2T, 4096, 1024, 4096,
                                                 nullptr, nullptr, nullptr, mp0, mp1, nullptr, nullptr);
  combine_mlp2<<<4096, 256, 0, stream>>>(x1, b2, mp0, mp1, out);
}

// Round 16
// 280.214 us; speedup vs baseline: 1.0917x; 1.0917x over previous
//
#include <hip/hip_runtime.h>

typedef unsigned short us16;
typedef __bf16 bf16x8 __attribute__((ext_vector_type(8)));
typedef float f32x2 __attribute__((ext_vector_type(2)));
typedef float f32x4 __attribute__((ext_vector_type(4)));
typedef float f32x16 __attribute__((ext_vector_type(16)));
typedef unsigned u32x4 __attribute__((ext_vector_type(4)));

#define DEV __device__ __forceinline__

DEV us16 f2bf(float x) {
  union { float f; unsigned u; } un; un.f = x;
  unsigned r = un.u + 0x7fffu + ((un.u >> 16) & 1u);
  return (us16)(r >> 16);
}
DEV float bf2f(us16 u) {
  union { unsigned u; float f; } x; x.u = ((unsigned)u) << 16; return x.f;
}
DEV float ex2(float x) { return __builtin_amdgcn_exp2f(x); }  // native v_exp_f32
DEV float gelu_f(float x) {
  // gelu(x) = x * sig(2*0.79788456*(x+0.044715x^3)); exp2 domain:
  // 2*0.7978845608*log2(e) = 2.3022082
  float e = ex2(2.3022082f * (x + 0.044715f * x * x * x));
  return x * (1.0f - 1.0f / (e + 1.0f));
}

DEV f32x16 mfma32(bf16x8 a, bf16x8 b, f32x16 c) {
  return __builtin_amdgcn_mfma_f32_32x32x16_bf16(a, b, c, 0, 0, 0);
}

DEV unsigned cvtpk_bf16(float lo, float hi) {
  unsigned r;
  asm("v_cvt_pk_bf16_f32 %0, %1, %2" : "=v"(r) : "v"(lo), "v"(hi));
  return r;
}
DEV void plswap(unsigned& x, unsigned& y) {
  asm("v_permlane32_swap_b32 %0, %1" : "+v"(x), "+v"(y));
}

// global -> LDS direct load, 16B per lane. LDS dest is wave-uniform base + lane*16.
DEV void gll16(const void* gp, void* lp) {
  __builtin_amdgcn_global_load_lds(
      (__attribute__((address_space(1))) unsigned int*)(unsigned long long)(gp),
      (__attribute__((address_space(3))) unsigned int*)(unsigned int)(unsigned long long)(lp),
      16, 0, 0);
}

// ---------------- prep: tp = gelu(time_emb) @ Wt + bt  -> tp[2][2048] ----------------
__global__ __launch_bounds__(256) void prep_tp(const float* __restrict__ te,
                                               const float* __restrict__ Wt,
                                               const float* __restrict__ bt,
                                               float* __restrict__ tp) {
  __shared__ float ge[1024];
  __shared__ float red[256];
  const int b = blockIdx.y, jt = blockIdx.x, t = threadIdx.x;
  for (int i = t; i < 1024; i += 256) ge[i] = gelu_f(te[b * 1024 + i]);
  __syncthreads();
  const int j = jt * 64 + (t & 63);
  const int dg = t >> 6;
  float acc = 0.f;
  for (int i = 0; i < 256; ++i) {
    int d = dg * 256 + i;
    acc += ge[d] * Wt[(size_t)d * 2048 + j];
  }
  red[t] = acc;
  __syncthreads();
  if (t < 64) tp[b * 2048 + jt * 64 + t] =
      red[t] + red[64 + t] + red[128 + t] + red[192 + t] + bt[jt * 64 + t];
}

// ---------------- weight cast+transpose: W[K][N] f32 -> Wt[N][K] bf16 ----------------
__global__ __launch_bounds__(256) void transpose_cast(const float* __restrict__ W,
                                                      us16* __restrict__ Wo,
                                                      int K, int N) {
  __shared__ float t[32][33];
  const int bn = blockIdx.x * 32, bk = blockIdx.y * 32;
  const int tx = threadIdx.x & 31, ty = threadIdx.x >> 5;
#pragma unroll
  for (int j = 0; j < 32; j += 8) t[ty + j][tx] = W[(size_t)(bk + ty + j) * N + bn + tx];
  __syncthreads();
#pragma unroll
  for (int j = 0; j < 32; j += 8) Wo[(size_t)(bn + ty + j) * K + bk + tx] = f2bf(t[tx][ty + j]);
}

// ---------------- LayerNorm (+ optional AdaLN modulation), f32 in -> bf16 out --------
template <int MOD>
__global__ __launch_bounds__(256) void ln_kernel(const float* __restrict__ x,
                                                 const float* __restrict__ gw,
                                                 const float* __restrict__ bw,
                                                 const float* __restrict__ tp,
                                                 us16* __restrict__ out) {
  const int row = blockIdx.x, b = row >> 11, t = threadIdx.x;
  const int lane = t & 63, wid = t >> 6;
  float4 xv = ((const float4*)(x + (size_t)row * 1024))[t];
  float s = xv.x + xv.y + xv.z + xv.w;
  float s2 = xv.x * xv.x + xv.y * xv.y + xv.z * xv.z + xv.w * xv.w;
#pragma unroll
  for (int o = 32; o; o >>= 1) { s += __shfl_xor(s, o); s2 += __shfl_xor(s2, o); }
  __shared__ float rs_[4], rq_[4];
  if (lane == 0) { rs_[wid] = s; rq_[wid] = s2; }
  __syncthreads();
  s = rs_[0] + rs_[1] + rs_[2] + rs_[3];
  s2 = rq_[0] + rq_[1] + rq_[2] + rq_[3];
  const float mu = s * 0.0009765625f;
  const float var = s2 * 0.0009765625f - mu * mu;
  const float rsig = rsqrtf(var + 1e-5f);
  float4 gv = ((const float4*)gw)[t], bv = ((const float4*)bw)[t];
  float y[4] = {(xv.x - mu) * rsig * gv.x + bv.x, (xv.y - mu) * rsig * gv.y + bv.y,
                (xv.z - mu) * rsig * gv.z + bv.z, (xv.w - mu) * rsig * gv.w + bv.w};
  if (MOD) {
    float4 sc = ((const float4*)(tp + b * 2048))[t];
    float4 sh = ((const float4*)(tp + b * 2048 + 1024))[t];
    y[0] = y[0] * (1.f + sc.x) + sh.x;
    y[1] = y[1] * (1.f + sc.y) + sh.y;
    y[2] = y[2] * (1.f + sc.z) + sh.z;
    y[3] = y[3] * (1.f + sc.w) + sh.w;
  }
  ushort4 o = {f2bf(y[0]), f2bf(y[1]), f2bf(y[2]), f2bf(y[3])};
  ((ushort4*)(out + (size_t)row * 1024))[t] = o;
}

// ---------------- dist permute: f32 [2048][2048] -> dp bf16 per-lane layout ----------
// dp[Q][t][ks][l][e] = dist[Q*32 + (l&31)][t*64 + ks*8 + (l>>5)*4 + e]
__global__ __launch_bounds__(256) void permute_dist(const float* __restrict__ dist,
                                                    us16* __restrict__ dp) {
  const int Q = blockIdx.x >> 3, part = blockIdx.x & 7;
  for (int j = threadIdx.x; j < 2048; j += 256) {
    int i = part * 2048 + j;
    int l = i & 63, ks = (i >> 6) & 7, t = i >> 9;
    int row = Q * 32 + (l & 31);
    int col = t * 64 + ks * 8 + (l >> 5) * 4;
    float4 v = *(const float4*)(dist + (size_t)row * 2048 + col);
    ushort4 o = {f2bf(v.x), f2bf(v.y), f2bf(v.z), f2bf(v.w)};
    *(ushort4*)(dp + ((size_t)Q * 16384 + i) * 4) = o;
  }
}

// ---------------- V transpose: v[bh][2048][64] -> vt[bh][64][2048] ----------------
__global__ __launch_bounds__(256) void transpose_v(const us16* __restrict__ v,
                                                   us16* __restrict__ vt) {
  __shared__ us16 t[64][72];
  const int bh = blockIdx.y, kv0 = blockIdx.x * 64;
  const int tid = threadIdx.x;
  const int r = tid >> 2, c0 = (tid & 3) * 16;
  const us16* src = v + ((size_t)bh * 2048 + kv0 + r) * 64 + c0;
  *(uint4*)&t[r][c0] = *(const uint4*)src;
  *(uint4*)&t[r][c0 + 8] = *(const uint4*)(src + 8);
  __syncthreads();
  const int d = tid >> 2, kvl = (tid & 3) * 16;
  us16 buf[16];
#pragma unroll
  for (int i = 0; i < 16; ++i) buf[i] = t[kvl + i][d];
  us16* dst = vt + ((size_t)bh * 64 + d) * 2048 + kv0 + kvl;
  *(uint4*)dst = *(uint4*)buf;
  *(uint4*)(dst + 8) = *(uint4*)(buf + 8);
}

// ---------------- GEMM: C[M][N] = A[M][K] @ Bt[N][K]^T, bf16 in, f32 acc -------------
// 32x32x16 MFMA. EPI 4 = split-K bf16 partials: z-slice g covers K/2, writes p_g.
template <int EPI>
__global__ __launch_bounds__(256) void gemm_bt(const us16* __restrict__ A,
                                               const us16* __restrict__ Bt,
                                               int M, int N, int K,
                                               const float* __restrict__ addf,
                                               const float* __restrict__ bias,
                                               float* __restrict__ outf,
                                               us16* __restrict__ outh,
                                               us16* __restrict__ qb,
                                               us16* __restrict__ kb,
                                               us16* __restrict__ vb) {
  __shared__ us16 Al[128 * 64];
  __shared__ us16 Bl[128 * 64];
  const int tid = threadIdx.x, lane = tid & 63, wid = tid >> 6;
  const int wm = wid >> 1, wn = wid & 1;
  const int nbx = gridDim.x, nwg = nbx * gridDim.y;
  const int idlin = blockIdx.y * nbx + blockIdx.x;
  const int wg = (idlin & 7) * (nwg >> 3) + (idlin >> 3);
  const int bm = wg / nbx, bn = wg % nbx;
  const int q31 = lane & 31, hi = lane >> 5;
  const int srow = lane >> 3;
  const int scol = ((lane & 7) ^ srow) << 3;

  f32x16 acc[2][2] = {};
  const size_t arow0 = (size_t)bm * 128 + wid * 32 + srow;
  const size_t brow0 = (size_t)bn * 128 + wid * 32 + srow;

  int kbeg = 0, kend = K;
  if (EPI == 4) { kbeg = blockIdx.z * (K >> 1); kend = kbeg + (K >> 1); }

  for (int k0 = kbeg; k0 < kend; k0 += 64) {
#pragma unroll
    for (int j = 0; j < 4; ++j) {
      gll16(A + (arow0 + j * 8) * K + k0 + scol, (char*)Al + (wid * 32 + j * 8) * 128);
      gll16(Bt + (brow0 + j * 8) * K + k0 + scol, (char*)Bl + (wid * 32 + j * 8) * 128);
    }
    __syncthreads();
#pragma unroll
    for (int ks = 0; ks < 4; ++ks) {
      const int cb = ks * 32 + hi * 16;
      bf16x8 af[2], bfr[2];
#pragma unroll
      for (int i = 0; i < 2; ++i) {
        int ra = wm * 64 + i * 32 + q31;
        af[i] = *(const bf16x8*)((const char*)Al + ra * 128 + (cb ^ ((ra & 7) << 4)));
        int rb = wn * 64 + i * 32 + q31;
        bfr[i] = *(const bf16x8*)((const char*)Bl + rb * 128 + (cb ^ ((rb & 7) << 4)));
      }
#pragma unroll
      for (int mi = 0; mi < 2; ++mi)
#pragma unroll
        for (int ni = 0; ni < 2; ++ni)
          acc[mi][ni] = mfma32(af[mi], bfr[ni], acc[mi][ni]);
    }
    __syncthreads();
  }

  us16* pd = nullptr;
  if (EPI == 4) pd = blockIdx.z == 0 ? outh : qb;

#pragma unroll
  for (int mi = 0; mi < 2; ++mi)
#pragma unroll
    for (int ni = 0; ni < 2; ++ni)
#pragma unroll
      for (int r = 0; r < 16; ++r) {
        int grow = bm * 128 + wm * 64 + mi * 32 + (r & 3) + 8 * (r >> 2) + 4 * hi;
        int gcol = bn * 128 + wn * 64 + ni * 32 + q31;
        float v = acc[mi][ni][r];
        if (EPI == 0) {
          int b = grow >> 11, lseq = grow & 2047;
          int which = gcol >> 10, hc = gcol & 1023;
          int hh = hc >> 6, d = hc & 63;
          size_t o = ((size_t)(b * 16 + hh) * 2048 + lseq) * 64 + d;
          if (which == 0) qb[o] = f2bf(v * 0.1803368801f);  // 0.125 * log2(e)
          else if (which == 1) kb[o] = f2bf(v);
          else vb[o] = f2bf(v);
        } else if (EPI == 1) {
          outh[(size_t)grow * N + gcol] = f2bf(gelu_f(v + bias[gcol]));
        } else if (EPI == 2) {
          size_t o = (size_t)grow * N + gcol;
          outf[o] = addf[o] + v;
        } else if (EPI == 4) {
          pd[(size_t)grow * N + gcol] = f2bf(v);
        } else {
          size_t o = (size_t)grow * N + gcol;
          outf[o] = addf[o] + bias[gcol] + v;
        }
      }
}

// ---------------- MLP2 combine: out = x1 + b2 + p0 + p1 ----------------
__global__ __launch_bounds__(256) void combine_mlp2(const float* __restrict__ x1,
                                                    const float* __restrict__ b2,
                                                    const us16* __restrict__ p0,
                                                    const us16* __restrict__ p1,
                                                    float* __restrict__ out) {
  const int row = blockIdx.x, t = threadIdx.x;
  const size_t base = (size_t)row * 1024 + t * 4;
  float4 xv = *(const float4*)(x1 + base);
  float4 bv = *(const float4*)(b2 + t * 4);
  ushort4 a = *(const ushort4*)(p0 + base);
  ushort4 b = *(const ushort4*)(p1 + base);
  float4 o;
  o.x = xv.x + bv.x + bf2f(a.x) + bf2f(b.x);
  o.y = xv.y + bv.y + bf2f(a.y) + bf2f(b.y);
  o.z = xv.z + bv.z + bf2f(a.z) + bf2f(b.z);
  o.w = xv.w + bv.w + bf2f(a.w) + bf2f(b.w);
  *(float4*)(out + base) = o;
}

// ---------------- flash attention: swapped-QK^T 32x32, exp2 (NATIVE v_exp), pk-f32 ---
// grid (qt=16, bh=32), qt fastest, no swizzle (R11 proven structure). 4 waves x 32
// q-rows; 32 kv tiles, unroll-2 ping-pong dist regs. __builtin_amdgcn_exp2f = native
// v_exp_f32 single instruction.
typedef union { f32x16 v; f32x2 p[8]; float f[16]; } F16U;

__global__ __launch_bounds__(256) void attn_kernel(const us16* __restrict__ q,
                                                   const us16* __restrict__ k,
                                                   const us16* __restrict__ vt,
                                                   const us16* __restrict__ dp,
                                                   const float* __restrict__ tscale,
                                                   us16* __restrict__ ctx) {
  __shared__ __align__(16) us16 Kl[2][64 * 64];
  __shared__ __align__(16) us16 Vl[2][64 * 64];
  __shared__ float als[128];
  const int tid = threadIdx.x, l = tid & 63, w4 = tid >> 6;
  const int q31 = l & 31, hi = l >> 5;
  const int qt = blockIdx.x, bh = blockIdx.y;
  const int b = bh >> 4, hh = bh & 15;
  const float scaleL = tscale[hh] * 1.44269504f;  // exp2 domain
  const int srow = l >> 3;
  const int scol = ((l & 7) ^ srow) << 3;
  const int q0blk = qt * 128;

  const us16* qg = q + ((size_t)bh * 2048 + q0blk + w4 * 32 + q31) * 64;
  bf16x8 qf[4];
#pragma unroll
  for (int kd = 0; kd < 4; ++kd) qf[kd] = *(const bf16x8*)(qg + kd * 16 + hi * 8);

  const us16* kpb = k + (size_t)bh * 2048 * 64;
  const us16* vpb = vt + (size_t)bh * 64 * 2048;
  const us16* dpw = dp + ((size_t)(qt * 4 + w4) * 16384 + l) * 4;

  f32x16 Oa = {}, Ob = {};
  float m = -1e30f, lsum = 0.f;
  ushort4 dA[8], dB[8];

  auto stage = [&](int kvn, int bufsel) {
#pragma unroll
    for (int j = 0; j < 2; ++j) {
      int row = w4 * 16 + j * 8 + srow;
      gll16(kpb + (size_t)(kvn + row) * 64 + scol, (char*)&Kl[bufsel][0] + (w4 * 16 + j * 8) * 128);
      gll16(vpb + (size_t)row * 2048 + kvn + scol, (char*)&Vl[bufsel][0] + (w4 * 16 + j * 8) * 128);
    }
  };
  auto load_d = [&](ushort4* dst, int tabs) {
#pragma unroll
    for (int ks = 0; ks < 8; ++ks) dst[ks] = *(const ushort4*)(dpw + (tabs * 8 + ks) * 256);
  };

  auto tile = [&](const us16* Kb, const us16* Vb, const ushort4* dc) {
    f32x16 SAv = {}, SBv = {};
#pragma unroll
    for (int kd = 0; kd < 4; ++kd) {
      const int cb = kd * 32 + hi * 16;
      const int r0 = q31, r1 = 32 + q31;
      bf16x8 ka = *(const bf16x8*)((const char*)Kb + r0 * 128 + (cb ^ ((r0 & 7) << 4)));
      bf16x8 kb2 = *(const bf16x8*)((const char*)Kb + r1 * 128 + (cb ^ ((r1 & 7) << 4)));
      SAv = mfma32(ka, qf[kd], SAv);
      SBv = mfma32(kb2, qf[kd], SBv);
    }
    F16U A, B2;
    A.v = SAv;
    B2.v = SBv;

    f32x2 t0 = __builtin_elementwise_max(__builtin_elementwise_max(A.p[0], A.p[1]),
                                         __builtin_elementwise_max(A.p[2], A.p[3]));
    f32x2 t1 = __builtin_elementwise_max(__builtin_elementwise_max(A.p[4], A.p[5]),
                                         __builtin_elementwise_max(A.p[6], A.p[7]));
    f32x2 t2 = __builtin_elementwise_max(__builtin_elementwise_max(B2.p[0], B2.p[1]),
                                         __builtin_elementwise_max(B2.p[2], B2.p[3]));
    f32x2 t3 = __builtin_elementwise_max(__builtin_elementwise_max(B2.p[4], B2.p[5]),
                                         __builtin_elementwise_max(B2.p[6], B2.p[7]));
    f32x2 tt = __builtin_elementwise_max(__builtin_elementwise_max(t0, t1),
                                         __builtin_elementwise_max(t2, t3));
    float pm = fmaxf(tt[0], tt[1]);
    pm = fmaxf(pm, __shfl_xor(pm, 32));

    if (__any(pm > m + 11.53f)) {  // 8 * log2(e)
      float mn = fmaxf(m, pm);
      float al = ex2(m - mn);
      m = mn;
      lsum *= al;
      if (!hi) als[w4 * 32 + q31] = al;
      f32x4 av[4];
#pragma unroll
      for (int g2 = 0; g2 < 4; ++g2) av[g2] = *(const f32x4*)&als[w4 * 32 + g2 * 8 + hi * 4];
#pragma unroll
      for (int g2 = 0; g2 < 4; ++g2)
#pragma unroll
        for (int e = 0; e < 4; ++e) {
          Oa[g2 * 4 + e] *= av[g2][e];
          Ob[g2 * 4 + e] *= av[g2][e];
        }
    }

    f32x2 nm = {-m, -m};
    f32x2 ns = {-scaleL, -scaleL};
#pragma unroll
    for (int ks = 0; ks < 4; ++ks) {
      ushort4 dlo = dc[ks], dhi = dc[ks + 4];
      f32x2 l0 = {bf2f(dlo.x), bf2f(dlo.y)};
      f32x2 l1 = {bf2f(dlo.z), bf2f(dlo.w)};
      f32x2 h0 = {bf2f(dhi.x), bf2f(dhi.y)};
      f32x2 h1 = {bf2f(dhi.z), bf2f(dhi.w)};
      A.p[ks * 2] = __builtin_elementwise_fma(ns, l0, A.p[ks * 2] + nm);
      A.p[ks * 2 + 1] = __builtin_elementwise_fma(ns, l1, A.p[ks * 2 + 1] + nm);
      B2.p[ks * 2] = __builtin_elementwise_fma(ns, h0, B2.p[ks * 2] + nm);
      B2.p[ks * 2 + 1] = __builtin_elementwise_fma(ns, h1, B2.p[ks * 2 + 1] + nm);
    }
#pragma unroll
    for (int i = 0; i < 16; ++i) {
      A.f[i] = ex2(A.f[i]);
      B2.f[i] = ex2(B2.f[i]);
    }

    f32x2 s = ((A.p[0] + A.p[1]) + (A.p[2] + A.p[3])) + ((A.p[4] + A.p[5]) + (A.p[6] + A.p[7]));
    s = s + (((B2.p[0] + B2.p[1]) + (B2.p[2] + B2.p[3])) +
             ((B2.p[4] + B2.p[5]) + (B2.p[6] + B2.p[7])));
    float rs = s[0] + s[1];
    rs += __shfl_xor(rs, 32);
    lsum += rs;

#pragma unroll
    for (int ks = 0; ks < 4; ++ks) {
      float p0, p1, p2, p3, p4, p5, p6, p7;
      if (ks == 0) { p0=A.f[0];p1=A.f[1];p2=A.f[2];p3=A.f[3];p4=A.f[4];p5=A.f[5];p6=A.f[6];p7=A.f[7]; }
      else if (ks == 1) { p0=A.f[8];p1=A.f[9];p2=A.f[10];p3=A.f[11];p4=A.f[12];p5=A.f[13];p6=A.f[14];p7=A.f[15]; }
      else if (ks == 2) { p0=B2.f[0];p1=B2.f[1];p2=B2.f[2];p3=B2.f[3];p4=B2.f[4];p5=B2.f[5];p6=B2.f[6];p7=B2.f[7]; }
      else { p0=B2.f[8];p1=B2.f[9];p2=B2.f[10];p3=B2.f[11];p4=B2.f[12];p5=B2.f[13];p6=B2.f[14];p7=B2.f[15]; }
      unsigned a = cvtpk_bf16(p0, p1), c = cvtpk_bf16(p2, p3);
      unsigned bb = cvtpk_bf16(p4, p5), dd = cvtpk_bf16(p6, p7);
      plswap(a, bb);
      plswap(c, dd);
      u32x4 fw;
      fw[0] = a; fw[1] = c; fw[2] = bb; fw[3] = dd;
      bf16x8 pf = __builtin_bit_cast(bf16x8, fw);
      const int cb = ks * 32 + hi * 16;
      const int rv0 = q31, rv1 = 32 + q31;
      bf16x8 v0 = *(const bf16x8*)((const char*)Vb + rv0 * 128 + (cb ^ ((rv0 & 7) << 4)));
      Oa = mfma32(pf, v0, Oa);
      bf16x8 v1 = *(const bf16x8*)((const char*)Vb + rv1 * 128 + (cb ^ ((rv1 & 7) << 4)));
      Ob = mfma32(pf, v1, Ob);
    }
  };

  // prologue
  stage(0, 0);
  load_d(dA, 0);
  __syncthreads();

  for (int t = 0; t < 32; t += 2) {
    stage((t + 1) * 64, 1);
    load_d(dB, t + 1);
    tile(&Kl[0][0], &Vl[0][0], dA);
    __syncthreads();
    if (t + 2 < 32) {
      stage((t + 2) * 64, 0);
      load_d(dA, t + 2);
    }
    tile(&Kl[1][0], &Vl[1][0], dB);
    __syncthreads();
  }

  // normalize + store
  float rl = 1.f / lsum;
  if (!hi) als[w4 * 32 + q31] = rl;
  f32x4 rv[4];
#pragma unroll
  for (int g2 = 0; g2 < 4; ++g2) rv[g2] = *(const f32x4*)&als[w4 * 32 + g2 * 8 + hi * 4];
  us16* cb_ = ctx + ((size_t)b * 2048 + q0blk + w4 * 32) * 1024 + hh * 64;
#pragma unroll
  for (int g2 = 0; g2 < 4; ++g2)
#pragma unroll
    for (int e = 0; e < 4; ++e) {
      int r = g2 * 4 + e;
      int qrow = g2 * 8 + hi * 4 + e;
      cb_[(size_t)qrow * 1024 + q31] = f2bf(Oa[r] * rv[g2][e]);
      cb_[(size_t)qrow * 1024 + 32 + q31] = f2bf(Ob[r] * rv[g2][e]);
    }
}

extern "C" void kernel_launch(void* const* d_in, const int* in_sizes, int n_in,
                              void* d_out, int out_size, void* d_ws, size_t ws_size,
                              hipStream_t stream) {
  const float* x    = (const float*)d_in[0];
  const float* dist = (const float*)d_in[1];
  const float* te   = (const float*)d_in[2];
  const float* ln1g = (const float*)d_in[4];
  const float* ln1b = (const float*)d_in[5];
  const float* Wqkv = (const float*)d_in[6];
  const float* Wout = (const float*)d_in[7];
  const float* tsc  = (const float*)d_in[8];
  const float* ln2g = (const float*)d_in[9];
  const float* ln2b = (const float*)d_in[10];
  const float* W1   = (const float*)d_in[11];
  const float* b1   = (const float*)d_in[12];
  const float* W2   = (const float*)d_in[13];
  const float* b2   = (const float*)d_in[14];
  const float* Wtm  = (const float*)d_in[15];
  const float* btm  = (const float*)d_in[16];
  float* out = (float*)d_out;
  (void)in_sizes; (void)n_in; (void)out_size; (void)ws_size;

  char* w = (char*)d_ws;
  size_t off = 0;
  auto alloc = [&](size_t bytes) { size_t o = off; off += (bytes + 255) & ~(size_t)255; return o; };
  float* tp  = (float*)(w + alloc((size_t)2 * 2048 * 4));
  us16* h    = (us16*)(w + alloc((size_t)4096 * 1024 * 2));
  us16* wqkvT= (us16*)(w + alloc((size_t)3072 * 1024 * 2));
  us16* woutT= (us16*)(w + alloc((size_t)1024 * 1024 * 2));
  us16* w1T  = (us16*)(w + alloc((size_t)4096 * 1024 * 2));
  us16* w2T  = (us16*)(w + alloc((size_t)1024 * 4096 * 2));
  us16* qb   = (us16*)(w + alloc((size_t)4 * 4096 * 1024 * 2));
  us16* kb   = qb + (size_t)4096 * 1024;
  us16* vb   = kb + (size_t)4096 * 1024;
  us16* vtb  = vb + (size_t)4096 * 1024;
  us16* gbuf = qb;  // reused after attention for MLP hidden [4096][4096]
  us16* dp   = (us16*)(w + alloc((size_t)2048 * 2048 * 2));
  us16* ctx  = (us16*)(w + alloc((size_t)4096 * 1024 * 2));
  float* x1  = (float*)(w + alloc((size_t)4096 * 1024 * 4));
  us16* h2   = (us16*)(w + alloc((size_t)4096 * 1024 * 2));
  us16* mp0  = dp;   // MLP2 split-K partials (dp free after attn)
  us16* mp1  = ctx;  // (ctx free after Wout gemm)

  prep_tp<<<dim3(32, 2), 256, 0, stream>>>(te, Wtm, btm, tp);
  transpose_cast<<<dim3(96, 32), 256, 0, stream>>>(Wqkv, wqkvT, 1024, 3072);
  transpose_cast<<<dim3(32, 32), 256, 0, stream>>>(Wout, woutT, 1024, 1024);
  transpose_cast<<<dim3(128, 32), 256, 0, stream>>>(W1, w1T, 1024, 4096);
  transpose_cast<<<dim3(32, 128), 256, 0, stream>>>(W2, w2T, 4096, 1024);
  ln_kernel<1><<<4096, 256, 0, stream>>>(x, ln1g, ln1b, tp, h);
  permute_dist<<<512, 256, 0, stream>>>(dist, dp);
  gemm_bt<0><<<dim3(24, 32), 256, 0, stream>>>(h, wqkvT, 4096, 3072, 1024,
                                               nullptr, nullptr, nullptr, nullptr, qb, kb, vb);
  transpose_v<<<dim3(32, 32), 256, 0, stream>>>(vb, vtb);
  attn_kernel<<<dim3(16, 32), 256, 0, stream>>>(qb, kb, vtb, dp, tsc, ctx);
  gemm_bt<2><<<dim3(8, 32), 256, 0, stream>>>(ctx, woutT, 4096, 1024, 1024,
                                              x, nullptr, x1, nullptr, nullptr, nullptr, nullptr);
  ln_kernel<0><<<4096, 256, 0, stream>>>(x1, ln2g, ln2b, nullptr, h2);
  gemm_bt<1><<<dim3(32, 32), 256, 0, stream>>>(h2, w1T, 4096, 4096, 1024,
                                               nullptr, b1, nullptr, gbuf, nullptr, nullptr, nullptr);
  gemm_bt<4><<<dim3(8, 32, 2), 256, 0, stream>>>(gbuf, w2T, 4096, 1024, 4096,
                                                 nullptr, nullptr, nullptr, mp0, mp1, nullptr, nullptr);
  combine_mlp2<<<4096, 256, 0, stream>>>(x1, b2, mp0, mp1, out);
}

// Round 17
// 275.397 us; speedup vs baseline: 1.1107x; 1.0175x over previous
//
#include <hip/hip_runtime.h>

typedef unsigned short us16;
typedef __bf16 bf16x8 __attribute__((ext_vector_type(8)));
typedef float f32x2 __attribute__((ext_vector_type(2)));
typedef float f32x4 __attribute__((ext_vector_type(4)));
typedef float f32x16 __attribute__((ext_vector_type(16)));
typedef unsigned u32x4 __attribute__((ext_vector_type(4)));

#define DEV __device__ __forceinline__

DEV us16 f2bf(float x) {
  union { float f; unsigned u; } un; un.f = x;
  unsigned r = un.u + 0x7fffu + ((un.u >> 16) & 1u);
  return (us16)(r >> 16);
}
DEV float bf2f(us16 u) {
  union { unsigned u; float f; } x; x.u = ((unsigned)u) << 16; return x.f;
}
DEV float ex2(float x) { return __builtin_amdgcn_exp2f(x); }  // native v_exp_f32
DEV float gelu_f(float x) {
  // gelu(x) = x * sig(2*0.79788456*(x+0.044715x^3)); exp2 domain const = 2.3022082
  float e = ex2(2.3022082f * (x + 0.044715f * x * x * x));
  return x * (1.0f - 1.0f / (e + 1.0f));
}

DEV f32x16 mfma32(bf16x8 a, bf16x8 b, f32x16 c) {
  return __builtin_amdgcn_mfma_f32_32x32x16_bf16(a, b, c, 0, 0, 0);
}

DEV unsigned cvtpk_bf16(float lo, float hi) {
  unsigned r;
  asm("v_cvt_pk_bf16_f32 %0, %1, %2" : "=v"(r) : "v"(lo), "v"(hi));
  return r;
}
DEV void plswap(unsigned& x, unsigned& y) {
  asm("v_permlane32_swap_b32 %0, %1" : "+v"(x), "+v"(y));
}

// global -> LDS direct load, 16B per lane. LDS dest is wave-uniform base + lane*16.
DEV void gll16(const void* gp, void* lp) {
  __builtin_amdgcn_global_load_lds(
      (__attribute__((address_space(1))) unsigned int*)(unsigned long long)(gp),
      (__attribute__((address_space(3))) unsigned int*)(unsigned int)(unsigned long long)(lp),
      16, 0, 0);
}

// ---------------- prep: tp = gelu(time_emb) @ Wt + bt  -> tp[2][2048] ----------------
__global__ __launch_bounds__(256) void prep_tp(const float* __restrict__ te,
                                               const float* __restrict__ Wt,
                                               const float* __restrict__ bt,
                                               float* __restrict__ tp) {
  __shared__ float ge[1024];
  __shared__ float red[256];
  const int b = blockIdx.y, jt = blockIdx.x, t = threadIdx.x;
  for (int i = t; i < 1024; i += 256) ge[i] = gelu_f(te[b * 1024 + i]);
  __syncthreads();
  const int j = jt * 64 + (t & 63);
  const int dg = t >> 6;
  float acc = 0.f;
  for (int i = 0; i < 256; ++i) {
    int d = dg * 256 + i;
    acc += ge[d] * Wt[(size_t)d * 2048 + j];
  }
  red[t] = acc;
  __syncthreads();
  if (t < 64) tp[b * 2048 + jt * 64 + t] =
      red[t] + red[64 + t] + red[128 + t] + red[192 + t] + bt[jt * 64 + t];
}

// ---------------- weight cast+transpose: W[K][N] f32 -> Wt[N][K] bf16 ----------------
__global__ __launch_bounds__(256) void transpose_cast(const float* __restrict__ W,
                                                      us16* __restrict__ Wo,
                                                      int K, int N) {
  __shared__ float t[32][33];
  const int bn = blockIdx.x * 32, bk = blockIdx.y * 32;
  const int tx = threadIdx.x & 31, ty = threadIdx.x >> 5;
#pragma unroll
  for (int j = 0; j < 32; j += 8) t[ty + j][tx] = W[(size_t)(bk + ty + j) * N + bn + tx];
  __syncthreads();
#pragma unroll
  for (int j = 0; j < 32; j += 8) Wo[(size_t)(bn + ty + j) * K + bk + tx] = f2bf(t[tx][ty + j]);
}

// ---------------- LayerNorm (+ optional AdaLN modulation), f32 in -> bf16 out --------
template <int MOD>
__global__ __launch_bounds__(256) void ln_kernel(const float* __restrict__ x,
                                                 const float* __restrict__ gw,
                                                 const float* __restrict__ bw,
                                                 const float* __restrict__ tp,
                                                 us16* __restrict__ out) {
  const int row = blockIdx.x, b = row >> 11, t = threadIdx.x;
  const int lane = t & 63, wid = t >> 6;
  float4 xv = ((const float4*)(x + (size_t)row * 1024))[t];
  float s = xv.x + xv.y + xv.z + xv.w;
  float s2 = xv.x * xv.x + xv.y * xv.y + xv.z * xv.z + xv.w * xv.w;
#pragma unroll
  for (int o = 32; o; o >>= 1) { s += __shfl_xor(s, o); s2 += __shfl_xor(s2, o); }
  __shared__ float rs_[4], rq_[4];
  if (lane == 0) { rs_[wid] = s; rq_[wid] = s2; }
  __syncthreads();
  s = rs_[0] + rs_[1] + rs_[2] + rs_[3];
  s2 = rq_[0] + rq_[1] + rq_[2] + rq_[3];
  const float mu = s * 0.0009765625f;
  const float var = s2 * 0.0009765625f - mu * mu;
  const float rsig = rsqrtf(var + 1e-5f);
  float4 gv = ((const float4*)gw)[t], bv = ((const float4*)bw)[t];
  float y[4] = {(xv.x - mu) * rsig * gv.x + bv.x, (xv.y - mu) * rsig * gv.y + bv.y,
                (xv.z - mu) * rsig * gv.z + bv.z, (xv.w - mu) * rsig * gv.w + bv.w};
  if (MOD) {
    float4 sc = ((const float4*)(tp + b * 2048))[t];
    float4 sh = ((const float4*)(tp + b * 2048 + 1024))[t];
    y[0] = y[0] * (1.f + sc.x) + sh.x;
    y[1] = y[1] * (1.f + sc.y) + sh.y;
    y[2] = y[2] * (1.f + sc.z) + sh.z;
    y[3] = y[3] * (1.f + sc.w) + sh.w;
  }
  ushort4 o = {f2bf(y[0]), f2bf(y[1]), f2bf(y[2]), f2bf(y[3])};
  ((ushort4*)(out + (size_t)row * 1024))[t] = o;
}

// ---------------- dist permute: f32 [2048][2048] -> dp bf16 per-lane layout ----------
// dp[Q][t][ks][l][e] = dist[Q*32 + (l&31)][t*64 + ks*8 + (l>>5)*4 + e]
__global__ __launch_bounds__(256) void permute_dist(const float* __restrict__ dist,
                                                    us16* __restrict__ dp) {
  const int Q = blockIdx.x >> 3, part = blockIdx.x & 7;
  for (int j = threadIdx.x; j < 2048; j += 256) {
    int i = part * 2048 + j;
    int l = i & 63, ks = (i >> 6) & 7, t = i >> 9;
    int row = Q * 32 + (l & 31);
    int col = t * 64 + ks * 8 + (l >> 5) * 4;
    float4 v = *(const float4*)(dist + (size_t)row * 2048 + col);
    ushort4 o = {f2bf(v.x), f2bf(v.y), f2bf(v.z), f2bf(v.w)};
    *(ushort4*)(dp + ((size_t)Q * 16384 + i) * 4) = o;
  }
}

// ---------------- GEMM: C[M][N] = A[M][K] @ Bt[N][K]^T, bf16 in, f32 acc -------------
// 32x32x16 MFMA. EPI 0: QKV scatter — V written DIRECTLY TRANSPOSED [bh][d][L] via
// ushort4 (lane's gcol=d fixed; 4-consecutive lseq runs; run never crosses batch
// boundary since growbase mod 32 in {0,4}). EPI 4 = split-K bf16 partials.
template <int EPI>
__global__ __launch_bounds__(256) void gemm_bt(const us16* __restrict__ A,
                                               const us16* __restrict__ Bt,
                                               int M, int N, int K,
                                               const float* __restrict__ addf,
                                               const float* __restrict__ bias,
                                               float* __restrict__ outf,
                                               us16* __restrict__ outh,
                                               us16* __restrict__ qb,
                                               us16* __restrict__ kb,
                                               us16* __restrict__ vtb) {
  __shared__ us16 Al[128 * 64];
  __shared__ us16 Bl[128 * 64];
  const int tid = threadIdx.x, lane = tid & 63, wid = tid >> 6;
  const int wm = wid >> 1, wn = wid & 1;
  const int nbx = gridDim.x, nwg = nbx * gridDim.y;
  const int idlin = blockIdx.y * nbx + blockIdx.x;
  const int wg = (idlin & 7) * (nwg >> 3) + (idlin >> 3);
  const int bm = wg / nbx, bn = wg % nbx;
  const int q31 = lane & 31, hi = lane >> 5;
  const int srow = lane >> 3;
  const int scol = ((lane & 7) ^ srow) << 3;

  f32x16 acc[2][2] = {};
  const size_t arow0 = (size_t)bm * 128 + wid * 32 + srow;
  const size_t brow0 = (size_t)bn * 128 + wid * 32 + srow;

  int kbeg = 0, kend = K;
  if (EPI == 4) { kbeg = blockIdx.z * (K >> 1); kend = kbeg + (K >> 1); }

  for (int k0 = kbeg; k0 < kend; k0 += 64) {
#pragma unroll
    for (int j = 0; j < 4; ++j) {
      gll16(A + (arow0 + j * 8) * K + k0 + scol, (char*)Al + (wid * 32 + j * 8) * 128);
      gll16(Bt + (brow0 + j * 8) * K + k0 + scol, (char*)Bl + (wid * 32 + j * 8) * 128);
    }
    __syncthreads();
#pragma unroll
    for (int ks = 0; ks < 4; ++ks) {
      const int cb = ks * 32 + hi * 16;
      bf16x8 af[2], bfr[2];
#pragma unroll
      for (int i = 0; i < 2; ++i) {
        int ra = wm * 64 + i * 32 + q31;
        af[i] = *(const bf16x8*)((const char*)Al + ra * 128 + (cb ^ ((ra & 7) << 4)));
        int rb = wn * 64 + i * 32 + q31;
        bfr[i] = *(const bf16x8*)((const char*)Bl + rb * 128 + (cb ^ ((rb & 7) << 4)));
      }
#pragma unroll
      for (int mi = 0; mi < 2; ++mi)
#pragma unroll
        for (int ni = 0; ni < 2; ++ni)
          acc[mi][ni] = mfma32(af[mi], bfr[ni], acc[mi][ni]);
    }
    __syncthreads();
  }

  us16* pd = nullptr;
  if (EPI == 4) pd = blockIdx.z == 0 ? outh : qb;

#pragma unroll
  for (int mi = 0; mi < 2; ++mi)
#pragma unroll
    for (int ni = 0; ni < 2; ++ni) {
      if (EPI == 0) {
        const int gcol = bn * 128 + wn * 64 + ni * 32 + q31;
        const int which = gcol >> 10, hc = gcol & 1023;
        const int hh = hc >> 6, d = hc & 63;
        const int growbase = bm * 128 + wm * 64 + mi * 32 + 4 * hi;
        if (which == 2) {
          const int b = growbase >> 11;
          us16* vrow = vtb + ((size_t)(b * 16 + hh) * 64 + d) * 2048;
#pragma unroll
          for (int g2 = 0; g2 < 4; ++g2) {
            int lseq = (growbase + 8 * g2) & 2047;
            int r0 = g2 * 4;
            ushort4 o = {f2bf(acc[mi][ni][r0]), f2bf(acc[mi][ni][r0 + 1]),
                         f2bf(acc[mi][ni][r0 + 2]), f2bf(acc[mi][ni][r0 + 3])};
            *(ushort4*)&vrow[lseq] = o;
          }
        } else {
#pragma unroll
          for (int r = 0; r < 16; ++r) {
            int grow = growbase + (r & 3) + 8 * (r >> 2);
            int b = grow >> 11, lseq = grow & 2047;
            size_t o = ((size_t)(b * 16 + hh) * 2048 + lseq) * 64 + d;
            float v = acc[mi][ni][r];
            if (which == 0) qb[o] = f2bf(v * 0.1803368801f);  // 0.125 * log2(e)
            else kb[o] = f2bf(v);
          }
        }
      } else {
#pragma unroll
        for (int r = 0; r < 16; ++r) {
          int grow = bm * 128 + wm * 64 + mi * 32 + (r & 3) + 8 * (r >> 2) + 4 * hi;
          int gcol = bn * 128 + wn * 64 + ni * 32 + q31;
          float v = acc[mi][ni][r];
          if (EPI == 1) {
            outh[(size_t)grow * N + gcol] = f2bf(gelu_f(v + bias[gcol]));
          } else if (EPI == 2) {
            size_t o = (size_t)grow * N + gcol;
            outf[o] = addf[o] + v;
          } else if (EPI == 4) {
            pd[(size_t)grow * N + gcol] = f2bf(v);
          } else {
            size_t o = (size_t)grow * N + gcol;
            outf[o] = addf[o] + bias[gcol] + v;
          }
        }
      }
    }
}

// ---------------- MLP2 combine: out = x1 + b2 + p0 + p1 ----------------
__global__ __launch_bounds__(256) void combine_mlp2(const float* __restrict__ x1,
                                                    const float* __restrict__ b2,
                                                    const us16* __restrict__ p0,
                                                    const us16* __restrict__ p1,
                                                    float* __restrict__ out) {
  const int row = blockIdx.x, t = threadIdx.x;
  const size_t base = (size_t)row * 1024 + t * 4;
  float4 xv = *(const float4*)(x1 + base);
  float4 bv = *(const float4*)(b2 + t * 4);
  ushort4 a = *(const ushort4*)(p0 + base);
  ushort4 b = *(const ushort4*)(p1 + base);
  float4 o;
  o.x = xv.x + bv.x + bf2f(a.x) + bf2f(b.x);
  o.y = xv.y + bv.y + bf2f(a.y) + bf2f(b.y);
  o.z = xv.z + bv.z + bf2f(a.z) + bf2f(b.z);
  o.w = xv.w + bv.w + bf2f(a.w) + bf2f(b.w);
  *(float4*)(out + base) = o;
}

// ---------------- flash attention: swapped-QK^T 32x32, native exp2, pk-f32 -----------
// grid (qt=16, bh=32), qt fastest, no swizzle. 4 waves x 32 q-rows; 32 kv tiles,
// unroll-2 ping-pong dist regs. (R16 proven structure, unchanged.)
typedef union { f32x16 v; f32x2 p[8]; float f[16]; } F16U;

__global__ __launch_bounds__(256) void attn_kernel(const us16* __restrict__ q,
                                                   const us16* __restrict__ k,
                                                   const us16* __restrict__ vt,
                                                   const us16* __restrict__ dp,
                                                   const float* __restrict__ tscale,
                                                   us16* __restrict__ ctx) {
  __shared__ __align__(16) us16 Kl[2][64 * 64];
  __shared__ __align__(16) us16 Vl[2][64 * 64];
  __shared__ float als[128];
  const int tid = threadIdx.x, l = tid & 63, w4 = tid >> 6;
  const int q31 = l & 31, hi = l >> 5;
  const int qt = blockIdx.x, bh = blockIdx.y;
  const int b = bh >> 4, hh = bh & 15;
  const float scaleL = tscale[hh] * 1.44269504f;  // exp2 domain
  const int srow = l >> 3;
  const int scol = ((l & 7) ^ srow) << 3;
  const int q0blk = qt * 128;

  const us16* qg = q + ((size_t)bh * 2048 + q0blk + w4 * 32 + q31) * 64;
  bf16x8 qf[4];
#pragma unroll
  for (int kd = 0; kd < 4; ++kd) qf[kd] = *(const bf16x8*)(qg + kd * 16 + hi * 8);

  const us16* kpb = k + (size_t)bh * 2048 * 64;
  const us16* vpb = vt + (size_t)bh * 64 * 2048;
  const us16* dpw = dp + ((size_t)(qt * 4 + w4) * 16384 + l) * 4;

  f32x16 Oa = {}, Ob = {};
  float m = -1e30f, lsum = 0.f;
  ushort4 dA[8], dB[8];

  auto stage = [&](int kvn, int bufsel) {
#pragma unroll
    for (int j = 0; j < 2; ++j) {
      int row = w4 * 16 + j * 8 + srow;
      gll16(kpb + (size_t)(kvn + row) * 64 + scol, (char*)&Kl[bufsel][0] + (w4 * 16 + j * 8) * 128);
      gll16(vpb + (size_t)row * 2048 + kvn + scol, (char*)&Vl[bufsel][0] + (w4 * 16 + j * 8) * 128);
    }
  };
  auto load_d = [&](ushort4* dst, int tabs) {
#pragma unroll
    for (int ks = 0; ks < 8; ++ks) dst[ks] = *(const ushort4*)(dpw + (tabs * 8 + ks) * 256);
  };

  auto tile = [&](const us16* Kb, const us16* Vb, const ushort4* dc) {
    f32x16 SAv = {}, SBv = {};
#pragma unroll
    for (int kd = 0; kd < 4; ++kd) {
      const int cb = kd * 32 + hi * 16;
      const int r0 = q31, r1 = 32 + q31;
      bf16x8 ka = *(const bf16x8*)((const char*)Kb + r0 * 128 + (cb ^ ((r0 & 7) << 4)));
      bf16x8 kb2 = *(const bf16x8*)((const char*)Kb + r1 * 128 + (cb ^ ((r1 & 7) << 4)));
      SAv = mfma32(ka, qf[kd], SAv);
      SBv = mfma32(kb2, qf[kd], SBv);
    }
    F16U A, B2;
    A.v = SAv;
    B2.v = SBv;

    f32x2 t0 = __builtin_elementwise_max(__builtin_elementwise_max(A.p[0], A.p[1]),
                                         __builtin_elementwise_max(A.p[2], A.p[3]));
    f32x2 t1 = __builtin_elementwise_max(__builtin_elementwise_max(A.p[4], A.p[5]),
                                         __builtin_elementwise_max(A.p[6], A.p[7]));
    f32x2 t2 = __builtin_elementwise_max(__builtin_elementwise_max(B2.p[0], B2.p[1]),
                                         __builtin_elementwise_max(B2.p[2], B2.p[3]));
    f32x2 t3 = __builtin_elementwise_max(__builtin_elementwise_max(B2.p[4], B2.p[5]),
                                         __builtin_elementwise_max(B2.p[6], B2.p[7]));
    f32x2 tt = __builtin_elementwise_max(__builtin_elementwise_max(t0, t1),
                                         __builtin_elementwise_max(t2, t3));
    float pm = fmaxf(tt[0], tt[1]);
    pm = fmaxf(pm, __shfl_xor(pm, 32));

    if (__any(pm > m + 11.53f)) {  // 8 * log2(e)
      float mn = fmaxf(m, pm);
      float al = ex2(m - mn);
      m = mn;
      lsum *= al;
      if (!hi) als[w4 * 32 + q31] = al;
      f32x4 av[4];
#pragma unroll
      for (int g2 = 0; g2 < 4; ++g2) av[g2] = *(const f32x4*)&als[w4 * 32 + g2 * 8 + hi * 4];
#pragma unroll
      for (int g2 = 0; g2 < 4; ++g2)
#pragma unroll
        for (int e = 0; e < 4; ++e) {
          Oa[g2 * 4 + e] *= av[g2][e];
          Ob[g2 * 4 + e] *= av[g2][e];
        }
    }

    f32x2 nm = {-m, -m};
    f32x2 ns = {-scaleL, -scaleL};
#pragma unroll
    for (int ks = 0; ks < 4; ++ks) {
      ushort4 dlo = dc[ks], dhi = dc[ks + 4];
      f32x2 l0 = {bf2f(dlo.x), bf2f(dlo.y)};
      f32x2 l1 = {bf2f(dlo.z), bf2f(dlo.w)};
      f32x2 h0 = {bf2f(dhi.x), bf2f(dhi.y)};
      f32x2 h1 = {bf2f(dhi.z), bf2f(dhi.w)};
      A.p[ks * 2] = __builtin_elementwise_fma(ns, l0, A.p[ks * 2] + nm);
      A.p[ks * 2 + 1] = __builtin_elementwise_fma(ns, l1, A.p[ks * 2 + 1] + nm);
      B2.p[ks * 2] = __builtin_elementwise_fma(ns, h0, B2.p[ks * 2] + nm);
      B2.p[ks * 2 + 1] = __builtin_elementwise_fma(ns, h1, B2.p[ks * 2 + 1] + nm);
    }
#pragma unroll
    for (int i = 0; i < 16; ++i) {
      A.f[i] = ex2(A.f[i]);
      B2.f[i] = ex2(B2.f[i]);
    }

    f32x2 s = ((A.p[0] + A.p[1]) + (A.p[2] + A.p[3])) + ((A.p[4] + A.p[5]) + (A.p[6] + A.p[7]));
    s = s + (((B2.p[0] + B2.p[1]) + (B2.p[2] + B2.p[3])) +
             ((B2.p[4] + B2.p[5]) + (B2.p[6] + B2.p[7])));
    float rs = s[0] + s[1];
    rs += __shfl_xor(rs, 32);
    lsum += rs;

#pragma unroll
    for (int ks = 0; ks < 4; ++ks) {
      float p0, p1, p2, p3, p4, p5, p6, p7;
      if (ks == 0) { p0=A.f[0];p1=A.f[1];p2=A.f[2];p3=A.f[3];p4=A.f[4];p5=A.f[5];p6=A.f[6];p7=A.f[7]; }
      else if (ks == 1) { p0=A.f[8];p1=A.f[9];p2=A.f[10];p3=A.f[11];p4=A.f[12];p5=A.f[13];p6=A.f[14];p7=A.f[15]; }
      else if (ks == 2) { p0=B2.f[0];p1=B2.f[1];p2=B2.f[2];p3=B2.f[3];p4=B2.f[4];p5=B2.f[5];p6=B2.f[6];p7=B2.f[7]; }
      else { p0=B2.f[8];p1=B2.f[9];p2=B2.f[10];p3=B2.f[11];p4=B2.f[12];p5=B2.f[13];p6=B2.f[14];p7=B2.f[15]; }
      unsigned a = cvtpk_bf16(p0, p1), c = cvtpk_bf16(p2, p3);
      unsigned bb = cvtpk_bf16(p4, p5), dd = cvtpk_bf16(p6, p7);
      plswap(a, bb);
      plswap(c, dd);
      u32x4 fw;
      fw[0] = a; fw[1] = c; fw[2] = bb; fw[3] = dd;
      bf16x8 pf = __builtin_bit_cast(bf16x8, fw);
      const int cb = ks * 32 + hi * 16;
      const int rv0 = q31, rv1 = 32 + q31;
      bf16x8 v0 = *(const bf16x8*)((const char*)Vb + rv0 * 128 + (cb ^ ((rv0 & 7) << 4)));
      Oa = mfma32(pf, v0, Oa);
      bf16x8 v1 = *(const bf16x8*)((const char*)Vb + rv1 * 128 + (cb ^ ((rv1 & 7) << 4)));
      Ob = mfma32(pf, v1, Ob);
    }
  };

  // prologue
  stage(0, 0);
  load_d(dA, 0);
  __syncthreads();

  for (int t = 0; t < 32; t += 2) {
    stage((t + 1) * 64, 1);
    load_d(dB, t + 1);
    tile(&Kl[0][0], &Vl[0][0], dA);
    __syncthreads();
    if (t + 2 < 32) {
      stage((t + 2) * 64, 0);
      load_d(dA, t + 2);
    }
    tile(&Kl[1][0], &Vl[1][0], dB);
    __syncthreads();
  }

  // normalize + store
  float rl = 1.f / lsum;
  if (!hi) als[w4 * 32 + q31] = rl;
  f32x4 rv[4];
#pragma unroll
  for (int g2 = 0; g2 < 4; ++g2) rv[g2] = *(const f32x4*)&als[w4 * 32 + g2 * 8 + hi * 4];
  us16* cb_ = ctx + ((size_t)b * 2048 + q0blk + w4 * 32) * 1024 + hh * 64;
#pragma unroll
  for (int g2 = 0; g2 < 4; ++g2)
#pragma unroll
    for (int e = 0; e < 4; ++e) {
      int r = g2 * 4 + e;
      int qrow = g2 * 8 + hi * 4 + e;
      cb_[(size_t)qrow * 1024 + q31] = f2bf(Oa[r] * rv[g2][e]);
      cb_[(size_t)qrow * 1024 + 32 + q31] = f2bf(Ob[r] * rv[g2][e]);
    }
}

extern "C" void kernel_launch(void* const* d_in, const int* in_sizes, int n_in,
                              void* d_out, int out_size, void* d_ws, size_t ws_size,
                              hipStream_t stream) {
  const float* x    = (const float*)d_in[0];
  const float* dist = (const float*)d_in[1];
  const float* te   = (const float*)d_in[2];
  const float* ln1g = (const float*)d_in[4];
  const float* ln1b = (const float*)d_in[5];
  const float* Wqkv = (const float*)d_in[6];
  const float* Wout = (const float*)d_in[7];
  const float* tsc  = (const float*)d_in[8];
  const float* ln2g = (const float*)d_in[9];
  const float* ln2b = (const float*)d_in[10];
  const float* W1   = (const float*)d_in[11];
  const float* b1   = (const float*)d_in[12];
  const float* W2   = (const float*)d_in[13];
  const float* b2   = (const float*)d_in[14];
  const float* Wtm  = (const float*)d_in[15];
  const float* btm  = (const float*)d_in[16];
  float* out = (float*)d_out;
  (void)in_sizes; (void)n_in; (void)out_size; (void)ws_size;

  char* w = (char*)d_ws;
  size_t off = 0;
  auto alloc = [&](size_t bytes) { size_t o = off; off += (bytes + 255) & ~(size_t)255; return o; };
  float* tp  = (float*)(w + alloc((size_t)2 * 2048 * 4));
  us16* h    = (us16*)(w + alloc((size_t)4096 * 1024 * 2));
  us16* wqkvT= (us16*)(w + alloc((size_t)3072 * 1024 * 2));
  us16* woutT= (us16*)(w + alloc((size_t)1024 * 1024 * 2));
  us16* w1T  = (us16*)(w + alloc((size_t)4096 * 1024 * 2));
  us16* w2T  = (us16*)(w + alloc((size_t)1024 * 4096 * 2));
  us16* qb   = (us16*)(w + alloc((size_t)4 * 4096 * 1024 * 2));
  us16* kb   = qb + (size_t)4096 * 1024;
  us16* vtb  = kb + (size_t)4096 * 1024;   // V written directly transposed [bh][d][L]
  us16* gbuf = qb;  // reused after attention for MLP hidden [4096][4096]
  us16* dp   = (us16*)(w + alloc((size_t)2048 * 2048 * 2));
  us16* ctx  = (us16*)(w + alloc((size_t)4096 * 1024 * 2));
  float* x1  = (float*)(w + alloc((size_t)4096 * 1024 * 4));
  us16* h2   = (us16*)(w + alloc((size_t)4096 * 1024 * 2));
  us16* mp0  = dp;   // MLP2 split-K partials (dp free after attn)
  us16* mp1  = ctx;  // (ctx free after Wout gemm)

  prep_tp<<<dim3(32, 2), 256, 0, stream>>>(te, Wtm, btm, tp);
  transpose_cast<<<dim3(96, 32), 256, 0, stream>>>(Wqkv, wqkvT, 1024, 3072);
  transpose_cast<<<dim3(32, 32), 256, 0, stream>>>(Wout, woutT, 1024, 1024);
  transpose_cast<<<dim3(128, 32), 256, 0, stream>>>(W1, w1T, 1024, 4096);
  transpose_cast<<<dim3(32, 128), 256, 0, stream>>>(W2, w2T, 4096, 1024);
  ln_kernel<1><<<4096, 256, 0, stream>>>(x, ln1g, ln1b, tp, h);
  permute_dist<<<512, 256, 0, stream>>>(dist, dp);
  gemm_bt<0><<<dim3(24, 32), 256, 0, stream>>>(h, wqkvT, 4096, 3072, 1024,
                                               nullptr, nullptr, nullptr, nullptr, qb, kb, vtb);
  attn_kernel<<<dim3(16, 32), 256, 0, stream>>>(qb, kb, vtb, dp, tsc, ctx);
  gemm_bt<2><<<dim3(8, 32), 256, 0, stream>>>(ctx, woutT, 4096, 1024, 1024,
                                              x, nullptr, x1, nullptr, nullptr, nullptr, nullptr);
  ln_kernel<0><<<4096, 256, 0, stream>>>(x1, ln2g, ln2b, nullptr, h2);
  gemm_bt<1><<<dim3(32, 32), 256, 0, stream>>>(h2, w1T, 4096, 4096, 1024,
                                               nullptr, b1, nullptr, gbuf, nullptr, nullptr, nullptr);
  gemm_bt<4><<<dim3(8, 32, 2), 256, 0, stream>>>(gbuf, w2T, 4096, 1024, 4096,
                                                 nullptr, nullptr, nullptr, mp0, mp1, nullptr, nullptr);
  combine_mlp2<<<4096, 256, 0, stream>>>(x1, b2, mp0, mp1, out);
}

// Round 18
// 273.312 us; speedup vs baseline: 1.1192x; 1.0076x over previous
//
#include <hip/hip_runtime.h>

typedef unsigned short us16;
typedef __bf16 bf16x8 __attribute__((ext_vector_type(8)));
typedef float f32x2 __attribute__((ext_vector_type(2)));
typedef float f32x4 __attribute__((ext_vector_type(4)));
typedef float f32x16 __attribute__((ext_vector_type(16)));
typedef unsigned u32x4 __attribute__((ext_vector_type(4)));

#define DEV __device__ __forceinline__

DEV us16 f2bf(float x) {
  union { float f; unsigned u; } un; un.f = x;
  unsigned r = un.u + 0x7fffu + ((un.u >> 16) & 1u);
  return (us16)(r >> 16);
}
DEV float bf2f(us16 u) {
  union { unsigned u; float f; } x; x.u = ((unsigned)u) << 16; return x.f;
}
DEV float ex2(float x) { return __builtin_amdgcn_exp2f(x); }  // native v_exp_f32
DEV float gelu_f(float x) {
  // gelu(x) = x * sig(2*0.79788456*(x+0.044715x^3)); exp2 domain const = 2.3022082
  float e = ex2(2.3022082f * (x + 0.044715f * x * x * x));
  return x * (1.0f - 1.0f / (e + 1.0f));
}

DEV f32x16 mfma32(bf16x8 a, bf16x8 b, f32x16 c) {
  return __builtin_amdgcn_mfma_f32_32x32x16_bf16(a, b, c, 0, 0, 0);
}

DEV unsigned cvtpk_bf16(float lo, float hi) {
  unsigned r;
  asm("v_cvt_pk_bf16_f32 %0, %1, %2" : "=v"(r) : "v"(lo), "v"(hi));
  return r;
}
DEV void plswap(unsigned& x, unsigned& y) {
  asm("v_permlane32_swap_b32 %0, %1" : "+v"(x), "+v"(y));
}

// global -> LDS direct load, 16B per lane. LDS dest is wave-uniform base + lane*16.
DEV void gll16(const void* gp, void* lp) {
  __builtin_amdgcn_global_load_lds(
      (__attribute__((address_space(1))) unsigned int*)(unsigned long long)(gp),
      (__attribute__((address_space(3))) unsigned int*)(unsigned int)(unsigned long long)(lp),
      16, 0, 0);
}

// ---------------- prep: tp = gelu(time_emb) @ Wt + bt  -> tp[2][2048] ----------------
__global__ __launch_bounds__(256) void prep_tp(const float* __restrict__ te,
                                               const float* __restrict__ Wt,
                                               const float* __restrict__ bt,
                                               float* __restrict__ tp) {
  __shared__ float ge[1024];
  __shared__ float red[256];
  const int b = blockIdx.y, jt = blockIdx.x, t = threadIdx.x;
  for (int i = t; i < 1024; i += 256) ge[i] = gelu_f(te[b * 1024 + i]);
  __syncthreads();
  const int j = jt * 64 + (t & 63);
  const int dg = t >> 6;
  float acc = 0.f;
  for (int i = 0; i < 256; ++i) {
    int d = dg * 256 + i;
    acc += ge[d] * Wt[(size_t)d * 2048 + j];
  }
  red[t] = acc;
  __syncthreads();
  if (t < 64) tp[b * 2048 + jt * 64 + t] =
      red[t] + red[64 + t] + red[128 + t] + red[192 + t] + bt[jt * 64 + t];
}

// ---------------- weight cast+transpose: W[K][N] f32 -> Wt[N][K] bf16 ----------------
__global__ __launch_bounds__(256) void transpose_cast(const float* __restrict__ W,
                                                      us16* __restrict__ Wo,
                                                      int K, int N) {
  __shared__ float t[32][33];
  const int bn = blockIdx.x * 32, bk = blockIdx.y * 32;
  const int tx = threadIdx.x & 31, ty = threadIdx.x >> 5;
#pragma unroll
  for (int j = 0; j < 32; j += 8) t[ty + j][tx] = W[(size_t)(bk + ty + j) * N + bn + tx];
  __syncthreads();
#pragma unroll
  for (int j = 0; j < 32; j += 8) Wo[(size_t)(bn + ty + j) * K + bk + tx] = f2bf(t[tx][ty + j]);
}

// ---------------- LayerNorm (+ optional AdaLN modulation), f32 in -> bf16 out --------
template <int MOD>
__global__ __launch_bounds__(256) void ln_kernel(const float* __restrict__ x,
                                                 const float* __restrict__ gw,
                                                 const float* __restrict__ bw,
                                                 const float* __restrict__ tp,
                                                 us16* __restrict__ out) {
  const int row = blockIdx.x, b = row >> 11, t = threadIdx.x;
  const int lane = t & 63, wid = t >> 6;
  float4 xv = ((const float4*)(x + (size_t)row * 1024))[t];
  float s = xv.x + xv.y + xv.z + xv.w;
  float s2 = xv.x * xv.x + xv.y * xv.y + xv.z * xv.z + xv.w * xv.w;
#pragma unroll
  for (int o = 32; o; o >>= 1) { s += __shfl_xor(s, o); s2 += __shfl_xor(s2, o); }
  __shared__ float rs_[4], rq_[4];
  if (lane == 0) { rs_[wid] = s; rq_[wid] = s2; }
  __syncthreads();
  s = rs_[0] + rs_[1] + rs_[2] + rs_[3];
  s2 = rq_[0] + rq_[1] + rq_[2] + rq_[3];
  const float mu = s * 0.0009765625f;
  const float var = s2 * 0.0009765625f - mu * mu;
  const float rsig = rsqrtf(var + 1e-5f);
  float4 gv = ((const float4*)gw)[t], bv = ((const float4*)bw)[t];
  float y[4] = {(xv.x - mu) * rsig * gv.x + bv.x, (xv.y - mu) * rsig * gv.y + bv.y,
                (xv.z - mu) * rsig * gv.z + bv.z, (xv.w - mu) * rsig * gv.w + bv.w};
  if (MOD) {
    float4 sc = ((const float4*)(tp + b * 2048))[t];
    float4 sh = ((const float4*)(tp + b * 2048 + 1024))[t];
    y[0] = y[0] * (1.f + sc.x) + sh.x;
    y[1] = y[1] * (1.f + sc.y) + sh.y;
    y[2] = y[2] * (1.f + sc.z) + sh.z;
    y[3] = y[3] * (1.f + sc.w) + sh.w;
  }
  ushort4 o = {f2bf(y[0]), f2bf(y[1]), f2bf(y[2]), f2bf(y[3])};
  ((ushort4*)(out + (size_t)row * 1024))[t] = o;
}

// ---------------- dist permute: f32 [2048][2048] -> dp bf16 per-lane layout ----------
// dp[Q][t][ks][l][e] = dist[Q*32 + (l&31)][t*64 + ks*8 + (l>>5)*4 + e]
__global__ __launch_bounds__(256) void permute_dist(const float* __restrict__ dist,
                                                    us16* __restrict__ dp) {
  const int Q = blockIdx.x >> 3, part = blockIdx.x & 7;
  for (int j = threadIdx.x; j < 2048; j += 256) {
    int i = part * 2048 + j;
    int l = i & 63, ks = (i >> 6) & 7, t = i >> 9;
    int row = Q * 32 + (l & 31);
    int col = t * 64 + ks * 8 + (l >> 5) * 4;
    float4 v = *(const float4*)(dist + (size_t)row * 2048 + col);
    ushort4 o = {f2bf(v.x), f2bf(v.y), f2bf(v.z), f2bf(v.w)};
    *(ushort4*)(dp + ((size_t)Q * 16384 + i) * 4) = o;
  }
}

// ---------------- GEMM: C[M][N] = A[M][K] @ Bt[N][K]^T, bf16 in, f32 acc -------------
// 32x32x16 MFMA. EPI 0: QKV scatter (V direct-transposed). EPI 4: split-K bf16
// partials (z-slice g covers K/2, writes outh/qb as p0/p1).
template <int EPI>
__global__ __launch_bounds__(256) void gemm_bt(const us16* __restrict__ A,
                                               const us16* __restrict__ Bt,
                                               int M, int N, int K,
                                               const float* __restrict__ addf,
                                               const float* __restrict__ bias,
                                               float* __restrict__ outf,
                                               us16* __restrict__ outh,
                                               us16* __restrict__ qb,
                                               us16* __restrict__ kb,
                                               us16* __restrict__ vtb) {
  __shared__ us16 Al[128 * 64];
  __shared__ us16 Bl[128 * 64];
  const int tid = threadIdx.x, lane = tid & 63, wid = tid >> 6;
  const int wm = wid >> 1, wn = wid & 1;
  const int nbx = gridDim.x, nwg = nbx * gridDim.y;
  const int idlin = blockIdx.y * nbx + blockIdx.x;
  const int wg = (idlin & 7) * (nwg >> 3) + (idlin >> 3);
  const int bm = wg / nbx, bn = wg % nbx;
  const int q31 = lane & 31, hi = lane >> 5;
  const int srow = lane >> 3;
  const int scol = ((lane & 7) ^ srow) << 3;

  f32x16 acc[2][2] = {};
  const size_t arow0 = (size_t)bm * 128 + wid * 32 + srow;
  const size_t brow0 = (size_t)bn * 128 + wid * 32 + srow;

  int kbeg = 0, kend = K;
  if (EPI == 4) { kbeg = blockIdx.z * (K >> 1); kend = kbeg + (K >> 1); }

  for (int k0 = kbeg; k0 < kend; k0 += 64) {
#pragma unroll
    for (int j = 0; j < 4; ++j) {
      gll16(A + (arow0 + j * 8) * K + k0 + scol, (char*)Al + (wid * 32 + j * 8) * 128);
      gll16(Bt + (brow0 + j * 8) * K + k0 + scol, (char*)Bl + (wid * 32 + j * 8) * 128);
    }
    __syncthreads();
#pragma unroll
    for (int ks = 0; ks < 4; ++ks) {
      const int cb = ks * 32 + hi * 16;
      bf16x8 af[2], bfr[2];
#pragma unroll
      for (int i = 0; i < 2; ++i) {
        int ra = wm * 64 + i * 32 + q31;
        af[i] = *(const bf16x8*)((const char*)Al + ra * 128 + (cb ^ ((ra & 7) << 4)));
        int rb = wn * 64 + i * 32 + q31;
        bfr[i] = *(const bf16x8*)((const char*)Bl + rb * 128 + (cb ^ ((rb & 7) << 4)));
      }
#pragma unroll
      for (int mi = 0; mi < 2; ++mi)
#pragma unroll
        for (int ni = 0; ni < 2; ++ni)
          acc[mi][ni] = mfma32(af[mi], bfr[ni], acc[mi][ni]);
    }
    __syncthreads();
  }

  us16* pd = nullptr;
  if (EPI == 4) pd = blockIdx.z == 0 ? outh : qb;

#pragma unroll
  for (int mi = 0; mi < 2; ++mi)
#pragma unroll
    for (int ni = 0; ni < 2; ++ni) {
      if (EPI == 0) {
        const int gcol = bn * 128 + wn * 64 + ni * 32 + q31;
        const int which = gcol >> 10, hc = gcol & 1023;
        const int hh = hc >> 6, d = hc & 63;
        const int growbase = bm * 128 + wm * 64 + mi * 32 + 4 * hi;
        if (which == 2) {
          const int b = growbase >> 11;
          us16* vrow = vtb + ((size_t)(b * 16 + hh) * 64 + d) * 2048;
#pragma unroll
          for (int g2 = 0; g2 < 4; ++g2) {
            int lseq = (growbase + 8 * g2) & 2047;
            int r0 = g2 * 4;
            ushort4 o = {f2bf(acc[mi][ni][r0]), f2bf(acc[mi][ni][r0 + 1]),
                         f2bf(acc[mi][ni][r0 + 2]), f2bf(acc[mi][ni][r0 + 3])};
            *(ushort4*)&vrow[lseq] = o;
          }
        } else {
#pragma unroll
          for (int r = 0; r < 16; ++r) {
            int grow = growbase + (r & 3) + 8 * (r >> 2);
            int b = grow >> 11, lseq = grow & 2047;
            size_t o = ((size_t)(b * 16 + hh) * 2048 + lseq) * 64 + d;
            float v = acc[mi][ni][r];
            if (which == 0) qb[o] = f2bf(v * 0.1803368801f);  // 0.125 * log2(e)
            else kb[o] = f2bf(v);
          }
        }
      } else {
#pragma unroll
        for (int r = 0; r < 16; ++r) {
          int grow = bm * 128 + wm * 64 + mi * 32 + (r & 3) + 8 * (r >> 2) + 4 * hi;
          int gcol = bn * 128 + wn * 64 + ni * 32 + q31;
          float v = acc[mi][ni][r];
          if (EPI == 1) {
            outh[(size_t)grow * N + gcol] = f2bf(gelu_f(v + bias[gcol]));
          } else if (EPI == 2) {
            size_t o = (size_t)grow * N + gcol;
            outf[o] = addf[o] + v;
          } else if (EPI == 4) {
            pd[(size_t)grow * N + gcol] = f2bf(v);
          } else {
            size_t o = (size_t)grow * N + gcol;
            outf[o] = addf[o] + bias[gcol] + v;
          }
        }
      }
    }
}

// ---------------- MLP2 combine: out = x1 + b2 + p0 + p1 ----------------
__global__ __launch_bounds__(256) void combine_mlp2(const float* __restrict__ x1,
                                                    const float* __restrict__ b2,
                                                    const us16* __restrict__ p0,
                                                    const us16* __restrict__ p1,
                                                    float* __restrict__ out) {
  const int row = blockIdx.x, t = threadIdx.x;
  const size_t base = (size_t)row * 1024 + t * 4;
  float4 xv = *(const float4*)(x1 + base);
  float4 bv = *(const float4*)(b2 + t * 4);
  ushort4 a = *(const ushort4*)(p0 + base);
  ushort4 b = *(const ushort4*)(p1 + base);
  float4 o;
  o.x = xv.x + bv.x + bf2f(a.x) + bf2f(b.x);
  o.y = xv.y + bv.y + bf2f(a.y) + bf2f(b.y);
  o.z = xv.z + bv.z + bf2f(a.z) + bf2f(b.z);
  o.w = xv.w + bv.w + bf2f(a.w) + bf2f(b.w);
  *(float4*)(out + base) = o;
}

// ---------------- Wout combine + LN2 fused: x1 = x + p0 + p1; h2 = LN(x1) ------------
__global__ __launch_bounds__(256) void combine_wout_ln2(const float* __restrict__ x,
                                                        const us16* __restrict__ p0,
                                                        const us16* __restrict__ p1,
                                                        const float* __restrict__ gw,
                                                        const float* __restrict__ bw,
                                                        float* __restrict__ x1,
                                                        us16* __restrict__ h2out) {
  const int row = blockIdx.x, t = threadIdx.x;
  const int lane = t & 63, wid = t >> 6;
  const size_t base = (size_t)row * 1024 + t * 4;
  float4 xv = *(const float4*)(x + base);
  ushort4 a = *(const ushort4*)(p0 + base);
  ushort4 b = *(const ushort4*)(p1 + base);
  float4 v;
  v.x = xv.x + bf2f(a.x) + bf2f(b.x);
  v.y = xv.y + bf2f(a.y) + bf2f(b.y);
  v.z = xv.z + bf2f(a.z) + bf2f(b.z);
  v.w = xv.w + bf2f(a.w) + bf2f(b.w);
  *(float4*)(x1 + base) = v;
  float s = v.x + v.y + v.z + v.w;
  float s2 = v.x * v.x + v.y * v.y + v.z * v.z + v.w * v.w;
#pragma unroll
  for (int o = 32; o; o >>= 1) { s += __shfl_xor(s, o); s2 += __shfl_xor(s2, o); }
  __shared__ float rs_[4], rq_[4];
  if (lane == 0) { rs_[wid] = s; rq_[wid] = s2; }
  __syncthreads();
  s = rs_[0] + rs_[1] + rs_[2] + rs_[3];
  s2 = rq_[0] + rq_[1] + rq_[2] + rq_[3];
  const float mu = s * 0.0009765625f;
  const float var = s2 * 0.0009765625f - mu * mu;
  const float rsig = rsqrtf(var + 1e-5f);
  float4 gv = ((const float4*)gw)[t], bv = ((const float4*)bw)[t];
  ushort4 o = {f2bf((v.x - mu) * rsig * gv.x + bv.x), f2bf((v.y - mu) * rsig * gv.y + bv.y),
               f2bf((v.z - mu) * rsig * gv.z + bv.z), f2bf((v.w - mu) * rsig * gv.w + bv.w)};
  ((ushort4*)(h2out + (size_t)row * 1024))[t] = o;
}

// ---------------- flash attention: swapped-QK^T 32x32, native exp2, pk-f32 -----------
// grid (qt=16, bh=32), qt fastest, no swizzle. 4 waves x 32 q-rows; 32 kv tiles,
// unroll-2 ping-pong dist regs. (R16 proven structure, unchanged.)
typedef union { f32x16 v; f32x2 p[8]; float f[16]; } F16U;

__global__ __launch_bounds__(256) void attn_kernel(const us16* __restrict__ q,
                                                   const us16* __restrict__ k,
                                                   const us16* __restrict__ vt,
                                                   const us16* __restrict__ dp,
                                                   const float* __restrict__ tscale,
                                                   us16* __restrict__ ctx) {
  __shared__ __align__(16) us16 Kl[2][64 * 64];
  __shared__ __align__(16) us16 Vl[2][64 * 64];
  __shared__ float als[128];
  const int tid = threadIdx.x, l = tid & 63, w4 = tid >> 6;
  const int q31 = l & 31, hi = l >> 5;
  const int qt = blockIdx.x, bh = blockIdx.y;
  const int b = bh >> 4, hh = bh & 15;
  const float scaleL = tscale[hh] * 1.44269504f;  // exp2 domain
  const int srow = l >> 3;
  const int scol = ((l & 7) ^ srow) << 3;
  const int q0blk = qt * 128;

  const us16* qg = q + ((size_t)bh * 2048 + q0blk + w4 * 32 + q31) * 64;
  bf16x8 qf[4];
#pragma unroll
  for (int kd = 0; kd < 4; ++kd) qf[kd] = *(const bf16x8*)(qg + kd * 16 + hi * 8);

  const us16* kpb = k + (size_t)bh * 2048 * 64;
  const us16* vpb = vt + (size_t)bh * 64 * 2048;
  const us16* dpw = dp + ((size_t)(qt * 4 + w4) * 16384 + l) * 4;

  f32x16 Oa = {}, Ob = {};
  float m = -1e30f, lsum = 0.f;
  ushort4 dA[8], dB[8];

  auto stage = [&](int kvn, int bufsel) {
#pragma unroll
    for (int j = 0; j < 2; ++j) {
      int row = w4 * 16 + j * 8 + srow;
      gll16(kpb + (size_t)(kvn + row) * 64 + scol, (char*)&Kl[bufsel][0] + (w4 * 16 + j * 8) * 128);
      gll16(vpb + (size_t)row * 2048 + kvn + scol, (char*)&Vl[bufsel][0] + (w4 * 16 + j * 8) * 128);
    }
  };
  auto load_d = [&](ushort4* dst, int tabs) {
#pragma unroll
    for (int ks = 0; ks < 8; ++ks) dst[ks] = *(const ushort4*)(dpw + (tabs * 8 + ks) * 256);
  };

  auto tile = [&](const us16* Kb, const us16* Vb, const ushort4* dc) {
    f32x16 SAv = {}, SBv = {};
#pragma unroll
    for (int kd = 0; kd < 4; ++kd) {
      const int cb = kd * 32 + hi * 16;
      const int r0 = q31, r1 = 32 + q31;
      bf16x8 ka = *(const bf16x8*)((const char*)Kb + r0 * 128 + (cb ^ ((r0 & 7) << 4)));
      bf16x8 kb2 = *(const bf16x8*)((const char*)Kb + r1 * 128 + (cb ^ ((r1 & 7) << 4)));
      SAv = mfma32(ka, qf[kd], SAv);
      SBv = mfma32(kb2, qf[kd], SBv);
    }
    F16U A, B2;
    A.v = SAv;
    B2.v = SBv;

    f32x2 t0 = __builtin_elementwise_max(__builtin_elementwise_max(A.p[0], A.p[1]),
                                         __builtin_elementwise_max(A.p[2], A.p[3]));
    f32x2 t1 = __builtin_elementwise_max(__builtin_elementwise_max(A.p[4], A.p[5]),
                                         __builtin_elementwise_max(A.p[6], A.p[7]));
    f32x2 t2 = __builtin_elementwise_max(__builtin_elementwise_max(B2.p[0], B2.p[1]),
                                         __builtin_elementwise_max(B2.p[2], B2.p[3]));
    f32x2 t3 = __builtin_elementwise_max(__builtin_elementwise_max(B2.p[4], B2.p[5]),
                                         __builtin_elementwise_max(B2.p[6], B2.p[7]));
    f32x2 tt = __builtin_elementwise_max(__builtin_elementwise_max(t0, t1),
                                         __builtin_elementwise_max(t2, t3));
    float pm = fmaxf(tt[0], tt[1]);
    pm = fmaxf(pm, __shfl_xor(pm, 32));

    if (__any(pm > m + 11.53f)) {  // 8 * log2(e)
      float mn = fmaxf(m, pm);
      float al = ex2(m - mn);
      m = mn;
      lsum *= al;
      if (!hi) als[w4 * 32 + q31] = al;
      f32x4 av[4];
#pragma unroll
      for (int g2 = 0; g2 < 4; ++g2) av[g2] = *(const f32x4*)&als[w4 * 32 + g2 * 8 + hi * 4];
#pragma unroll
      for (int g2 = 0; g2 < 4; ++g2)
#pragma unroll
        for (int e = 0; e < 4; ++e) {
          Oa[g2 * 4 + e] *= av[g2][e];
          Ob[g2 * 4 + e] *= av[g2][e];
        }
    }

    f32x2 nm = {-m, -m};
    f32x2 ns = {-scaleL, -scaleL};
#pragma unroll
    for (int ks = 0; ks < 4; ++ks) {
      ushort4 dlo = dc[ks], dhi = dc[ks + 4];
      f32x2 l0 = {bf2f(dlo.x), bf2f(dlo.y)};
      f32x2 l1 = {bf2f(dlo.z), bf2f(dlo.w)};
      f32x2 h0 = {bf2f(dhi.x), bf2f(dhi.y)};
      f32x2 h1 = {bf2f(dhi.z), bf2f(dhi.w)};
      A.p[ks * 2] = __builtin_elementwise_fma(ns, l0, A.p[ks * 2] + nm);
      A.p[ks * 2 + 1] = __builtin_elementwise_fma(ns, l1, A.p[ks * 2 + 1] + nm);
      B2.p[ks * 2] = __builtin_elementwise_fma(ns, h0, B2.p[ks * 2] + nm);
      B2.p[ks * 2 + 1] = __builtin_elementwise_fma(ns, h1, B2.p[ks * 2 + 1] + nm);
    }
#pragma unroll
    for (int i = 0; i < 16; ++i) {
      A.f[i] = ex2(A.f[i]);
      B2.f[i] = ex2(B2.f[i]);
    }

    f32x2 s = ((A.p[0] + A.p[1]) + (A.p[2] + A.p[3])) + ((A.p[4] + A.p[5]) + (A.p[6] + A.p[7]));
    s = s + (((B2.p[0] + B2.p[1]) + (B2.p[2] + B2.p[3])) +
             ((B2.p[4] + B2.p[5]) + (B2.p[6] + B2.p[7])));
    float rs = s[0] + s[1];
    rs += __shfl_xor(rs, 32);
    lsum += rs;

#pragma unroll
    for (int ks = 0; ks < 4; ++ks) {
      float p0, p1, p2, p3, p4, p5, p6, p7;
      if (ks == 0) { p0=A.f[0];p1=A.f[1];p2=A.f[2];p3=A.f[3];p4=A.f[4];p5=A.f[5];p6=A.f[6];p7=A.f[7]; }
      else if (ks == 1) { p0=A.f[8];p1=A.f[9];p2=A.f[10];p3=A.f[11];p4=A.f[12];p5=A.f[13];p6=A.f[14];p7=A.f[15]; }
      else if (ks == 2) { p0=B2.f[0];p1=B2.f[1];p2=B2.f[2];p3=B2.f[3];p4=B2.f[4];p5=B2.f[5];p6=B2.f[6];p7=B2.f[7]; }
      else { p0=B2.f[8];p1=B2.f[9];p2=B2.f[10];p3=B2.f[11];p4=B2.f[12];p5=B2.f[13];p6=B2.f[14];p7=B2.f[15]; }
      unsigned a = cvtpk_bf16(p0, p1), c = cvtpk_bf16(p2, p3);
      unsigned bb = cvtpk_bf16(p4, p5), dd = cvtpk_bf16(p6, p7);
      plswap(a, bb);
      plswap(c, dd);
      u32x4 fw;
      fw[0] = a; fw[1] = c; fw[2] = bb; fw[3] = dd;
      bf16x8 pf = __builtin_bit_cast(bf16x8, fw);
      const int cb = ks * 32 + hi * 16;
      const int rv0 = q31, rv1 = 32 + q31;
      bf16x8 v0 = *(const bf16x8*)((const char*)Vb + rv0 * 128 + (cb ^ ((rv0 & 7) << 4)));
      Oa = mfma32(pf, v0, Oa);
      bf16x8 v1 = *(const bf16x8*)((const char*)Vb + rv1 * 128 + (cb ^ ((rv1 & 7) << 4)));
      Ob = mfma32(pf, v1, Ob);
    }
  };

  // prologue
  stage(0, 0);
  load_d(dA, 0);
  __syncthreads();

  for (int t = 0; t < 32; t += 2) {
    stage((t + 1) * 64, 1);
    load_d(dB, t + 1);
    tile(&Kl[0][0], &Vl[0][0], dA);
    __syncthreads();
    if (t + 2 < 32) {
      stage((t + 2) * 64, 0);
      load_d(dA, t + 2);
    }
    tile(&Kl[1][0], &Vl[1][0], dB);
    __syncthreads();
  }

  // normalize + store
  float rl = 1.f / lsum;
  if (!hi) als[w4 * 32 + q31] = rl;
  f32x4 rv[4];
#pragma unroll
  for (int g2 = 0; g2 < 4; ++g2) rv[g2] = *(const f32x4*)&als[w4 * 32 + g2 * 8 + hi * 4];
  us16* cb_ = ctx + ((size_t)b * 2048 + q0blk + w4 * 32) * 1024 + hh * 64;
#pragma unroll
  for (int g2 = 0; g2 < 4; ++g2)
#pragma unroll
    for (int e = 0; e < 4; ++e) {
      int r = g2 * 4 + e;
      int qrow = g2 * 8 + hi * 4 + e;
      cb_[(size_t)qrow * 1024 + q31] = f2bf(Oa[r] * rv[g2][e]);
      cb_[(size_t)qrow * 1024 + 32 + q31] = f2bf(Ob[r] * rv[g2][e]);
    }
}

extern "C" void kernel_launch(void* const* d_in, const int* in_sizes, int n_in,
                              void* d_out, int out_size, void* d_ws, size_t ws_size,
                              hipStream_t stream) {
  const float* x    = (const float*)d_in[0];
  const float* dist = (const float*)d_in[1];
  const float* te   = (const float*)d_in[2];
  const float* ln1g = (const float*)d_in[4];
  const float* ln1b = (const float*)d_in[5];
  const float* Wqkv = (const float*)d_in[6];
  const float* Wout = (const float*)d_in[7];
  const float* tsc  = (const float*)d_in[8];
  const float* ln2g = (const float*)d_in[9];
  const float* ln2b = (const float*)d_in[10];
  const float* W1   = (const float*)d_in[11];
  const float* b1   = (const float*)d_in[12];
  const float* W2   = (const float*)d_in[13];
  const float* b2   = (const float*)d_in[14];
  const float* Wtm  = (const float*)d_in[15];
  const float* btm  = (const float*)d_in[16];
  float* out = (float*)d_out;
  (void)in_sizes; (void)n_in; (void)out_size; (void)ws_size;

  char* w = (char*)d_ws;
  size_t off = 0;
  auto alloc = [&](size_t bytes) { size_t o = off; off += (bytes + 255) & ~(size_t)255; return o; };
  float* tp  = (float*)(w + alloc((size_t)2 * 2048 * 4));
  us16* h    = (us16*)(w + alloc((size_t)4096 * 1024 * 2));
  us16* wqkvT= (us16*)(w + alloc((size_t)3072 * 1024 * 2));
  us16* woutT= (us16*)(w + alloc((size_t)1024 * 1024 * 2));
  us16* w1T  = (us16*)(w + alloc((size_t)4096 * 1024 * 2));
  us16* w2T  = (us16*)(w + alloc((size_t)1024 * 4096 * 2));
  us16* qb   = (us16*)(w + alloc((size_t)4 * 4096 * 1024 * 2));
  us16* kb   = qb + (size_t)4096 * 1024;
  us16* vtb  = kb + (size_t)4096 * 1024;   // V written directly transposed [bh][d][L]
  us16* gbuf = qb;  // reused after Wout-combine for MLP hidden [4096][4096]
  us16* dp   = (us16*)(w + alloc((size_t)2048 * 2048 * 2));
  us16* ctx  = (us16*)(w + alloc((size_t)4096 * 1024 * 2));
  float* x1  = (float*)(w + alloc((size_t)4096 * 1024 * 4));
  us16* h2   = (us16*)(w + alloc((size_t)4096 * 1024 * 2));
  us16* wp0  = qb;   // Wout split-K partials (qb/kb free after attn; consumed before MLP1)
  us16* wp1  = kb;
  us16* mp0  = dp;   // MLP2 split-K partials (dp free after attn)
  us16* mp1  = ctx;  // (ctx free after Wout gemm)

  prep_tp<<<dim3(32, 2), 256, 0, stream>>>(te, Wtm, btm, tp);
  transpose_cast<<<dim3(96, 32), 256, 0, stream>>>(Wqkv, wqkvT, 1024, 3072);
  transpose_cast<<<dim3(32, 32), 256, 0, stream>>>(Wout, woutT, 1024, 1024);
  transpose_cast<<<dim3(128, 32), 256, 0, stream>>>(W1, w1T, 1024, 4096);
  transpose_cast<<<dim3(32, 128), 256, 0, stream>>>(W2, w2T, 4096, 1024);
  ln_kernel<1><<<4096, 256, 0, stream>>>(x, ln1g, ln1b, tp, h);
  permute_dist<<<512, 256, 0, stream>>>(dist, dp);
  gemm_bt<0><<<dim3(24, 32), 256, 0, stream>>>(h, wqkvT, 4096, 3072, 1024,
                                               nullptr, nullptr, nullptr, nullptr, qb, kb, vtb);
  attn_kernel<<<dim3(16, 32), 256, 0, stream>>>(qb, kb, vtb, dp, tsc, ctx);
  gemm_bt<4><<<dim3(8, 32, 2), 256, 0, stream>>>(ctx, woutT, 4096, 1024, 1024,
                                                 nullptr, nullptr, nullptr, wp0, wp1, nullptr, nullptr);
  combine_wout_ln2<<<4096, 256, 0, stream>>>(x, wp0, wp1, ln2g, ln2b, x1, h2);
  gemm_bt<1><<<dim3(32, 32), 256, 0, stream>>>(h2, w1T, 4096, 4096, 1024,
                                               nullptr, b1, nullptr, gbuf, nullptr, nullptr, nullptr);
  gemm_bt<4><<<dim3(8, 32, 2), 256, 0, stream>>>(gbuf, w2T, 4096, 1024, 4096,
                                                 nullptr, nullptr, nullptr, mp0, mp1, nullptr, nullptr);
  combine_mlp2<<<4096, 256, 0, stream>>>(x1, b2, mp0, mp1, out);
}